// Round 7
// baseline (481.125 us; speedup 1.0000x reference)
//
#include <hip/hip_runtime.h>
#include <hip/hip_bf16.h>
#include <stdint.h>

typedef short short8 __attribute__((ext_vector_type(8)));
typedef float f32x4 __attribute__((ext_vector_type(4)));
typedef float fvec4 __attribute__((ext_vector_type(4)));
typedef unsigned short us4 __attribute__((ext_vector_type(4)));
typedef unsigned short us8 __attribute__((ext_vector_type(8)));

static __device__ __forceinline__ unsigned short f2bf(float f) {
  union { float f; uint32_t u; } v; v.f = f;
  uint32_t u = v.u;
  return (unsigned short)((u + 0x7FFFu + ((u >> 16) & 1u)) >> 16);
}

static __device__ __forceinline__ float bf2f(unsigned short u) {
  union { uint32_t u; float f; } v; v.u = (uint32_t)u << 16;
  return v.f;
}

// fast ELU: __expf -> v_exp_f32. |err| ~1e-7, fine vs 2e-2 threshold.
static __device__ __forceinline__ float elu_f(float v) {
  return v > 0.0f ? v : __expf(v) - 1.0f;
}

// Pack all 4 weight matrices into MFMA B-fragment order (bf16), one launch.
__global__ void pack_all_kernel(const float* __restrict__ W1a, const float* __restrict__ W1b,
                                const float* __restrict__ W2a, const float* __restrict__ W2b,
                                unsigned short* __restrict__ w1aP, unsigned short* __restrict__ w1bP,
                                unsigned short* __restrict__ w2aP, unsigned short* __restrict__ w2bP) {
  int p = blockIdx.x * blockDim.x + threadIdx.x;
  const float* W; unsigned short* dst; int KT, Nc, q;
  if (p < 65536)       { W = W1a; dst = w1aP; KT = 8;  Nc = 256; q = p; }
  else if (p < 131072) { W = W1b; dst = w1bP; KT = 8;  Nc = 256; q = p - 65536; }
  else if (p < 229376) { W = W2a; dst = w2aP; KT = 12; Nc = 256; q = p - 131072; }
  else                 { W = W2b; dst = w2bP; KT = 8;  Nc = 128; q = p - 229376; }
  int i = q & 7;
  int l = (q >> 3) & 63;
  int rest = q >> 9;
  int kt = rest % KT;
  int nt = rest / KT;
  dst[q] = f2bf(W[(size_t)(kt * 32 + (l >> 4) * 8 + i) * Nc + nt * 16 + (l & 15)]);
}

__global__ void hist_kernel(const int* __restrict__ col_idx, int* __restrict__ cnt, int E) {
  int i = blockIdx.x * blockDim.x + threadIdx.x;
  if (i < E) atomicAdd(&cnt[col_idx[i]], 1);
}

// single-launch scan: each thread serially owns a chunk, one 1024-wide block scan.
__global__ __launch_bounds__(1024) void scan_kernel(const int* __restrict__ cnt,
                                                    int* __restrict__ startA,
                                                    int* __restrict__ offs, int N, int E) {
  __shared__ int partial[1024];
  const int t = threadIdx.x;
  const int chunk = (N + 1023) >> 10;
  const int base = t * chunk;
  int s = 0;
  for (int i = 0; i < chunk; ++i) {
    int idx = base + i;
    if (idx < N) s += cnt[idx];
  }
  partial[t] = s;
  __syncthreads();
  for (int o = 1; o < 1024; o <<= 1) {
    int a = (t >= o) ? partial[t - o] : 0;
    __syncthreads();
    partial[t] += a;
    __syncthreads();
  }
  int run = partial[t] - s;
  for (int i = 0; i < chunk; ++i) {
    int idx = base + i;
    if (idx < N) {
      startA[idx] = run;
      offs[idx] = run;
      run += cnt[idx];
    }
  }
  if (t == 0) startA[N] = E;
}

// build dst-sorted edge list: eid[csr_slot] = edge
__global__ void eid_kernel(const int* __restrict__ col_idx, int* __restrict__ offs,
                           int* __restrict__ eid, int E) {
  int i = blockIdx.x * blockDim.x + threadIdx.x;
  if (i < E) eid[atomicAdd(&offs[col_idx[i]], 1)] = i;
}

#define LDA 264  // 256 + 8 pad (bf16 elems); 528B row stride, 16B aligned

// 64 edges/block, 4 waves; wave w owns output cols [64w, 64w+64).
// Writes h in EDGE ORDER (streaming, no scatter).
__global__ __launch_bounds__(256, 4) void edge_mlp_kernel(
    const float* __restrict__ x, const int* __restrict__ row_idx,
    const float* __restrict__ eattr, const float* __restrict__ b1a,
    const unsigned short* __restrict__ w1aP, const unsigned short* __restrict__ w1bP,
    unsigned short* __restrict__ hsort) {
  __shared__ __align__(16) unsigned short As[64 * LDA];
  __shared__ int rowi[64];
  const int t = threadIdx.x;
  const int e0 = blockIdx.x * 64;

  if (t < 64) rowi[t] = row_idx[e0 + t];

  const int w = t >> 6, l = t & 63;
  const int lr = l & 15, lk = l >> 4;
  const unsigned short* B1 = w1aP + (size_t)(w * 32) * 512 + (size_t)l * 8;
  const unsigned short* B2 = w1bP + (size_t)(w * 32) * 512 + (size_t)l * 8;

  short8 bA[4], bB[4];
#pragma unroll
  for (int n = 0; n < 4; ++n) bA[n] = *(const short8*)(B1 + n * 4096);

  __syncthreads();

  // stage A: [64 edges][256 feats] as bf16 (x[row] | edge_attr)
  for (int idx = t; idx < 64 * 64; idx += 256) {
    int e = idx >> 6, c4 = idx & 63;
    fvec4 v;
    if (c4 < 32)
      v = *(const fvec4*)(x + (size_t)rowi[e] * 128 + c4 * 4);
    else
      v = __builtin_nontemporal_load((const fvec4*)(eattr + (size_t)(e0 + e) * 128 + (c4 - 32) * 4));
    us4 o;
    o.x = f2bf(v.x); o.y = f2bf(v.y); o.z = f2bf(v.z); o.w = f2bf(v.w);
    *(us4*)(&As[e * LDA + c4 * 4]) = o;
  }
  __syncthreads();

  f32x4 acc[4][4];
  const f32x4 zero4 = {0.f, 0.f, 0.f, 0.f};
#pragma unroll
  for (int mt = 0; mt < 4; ++mt)
#pragma unroll
    for (int nt = 0; nt < 4; ++nt) acc[mt][nt] = zero4;

  // GEMM1: [64,256] x W1a[256,256], B double-buffered
#pragma unroll
  for (int kt = 0; kt < 8; ++kt) {
    short8* bc = (kt & 1) ? bB : bA;
    short8* bn = (kt & 1) ? bA : bB;
    if (kt < 7) {
#pragma unroll
      for (int n = 0; n < 4; ++n) bn[n] = *(const short8*)(B1 + n * 4096 + (kt + 1) * 512);
    }
    short8 a[4];
#pragma unroll
    for (int mt = 0; mt < 4; ++mt)
      a[mt] = *(const short8*)(&As[(mt * 16 + lr) * LDA + kt * 32 + lk * 8]);
#pragma unroll
    for (int mt = 0; mt < 4; ++mt)
#pragma unroll
      for (int nt = 0; nt < 4; ++nt)
        acc[mt][nt] = __builtin_amdgcn_mfma_f32_16x16x32_bf16(a[mt], bc[nt], acc[mt][nt], 0, 0, 0);
  }

#pragma unroll
  for (int n = 0; n < 4; ++n) bA[n] = *(const short8*)(B2 + n * 4096);

  __syncthreads();

  // epilogue1: bias + ELU -> bf16 H (reuse As)
#pragma unroll
  for (int nt = 0; nt < 4; ++nt) {
    int col = w * 64 + nt * 16 + lr;
    float bias = b1a[col];
#pragma unroll
    for (int mt = 0; mt < 4; ++mt)
#pragma unroll
      for (int j = 0; j < 4; ++j) {
        float v = elu_f(acc[mt][nt][j] + bias);
        As[(mt * 16 + lk * 4 + j) * LDA + col] = f2bf(v);
      }
  }
  __syncthreads();

  // GEMM2: H[64,256] x W1b[256,256]
#pragma unroll
  for (int mt = 0; mt < 4; ++mt)
#pragma unroll
    for (int nt = 0; nt < 4; ++nt) acc[mt][nt] = zero4;
#pragma unroll
  for (int kt = 0; kt < 8; ++kt) {
    short8* bc = (kt & 1) ? bB : bA;
    short8* bn = (kt & 1) ? bA : bB;
    if (kt < 7) {
#pragma unroll
      for (int n = 0; n < 4; ++n) bn[n] = *(const short8*)(B2 + n * 4096 + (kt + 1) * 512);
    }
    short8 a[4];
#pragma unroll
    for (int mt = 0; mt < 4; ++mt)
      a[mt] = *(const short8*)(&As[(mt * 16 + lr) * LDA + kt * 32 + lk * 8]);
#pragma unroll
    for (int mt = 0; mt < 4; ++mt)
#pragma unroll
      for (int nt = 0; nt < 4; ++nt)
        acc[mt][nt] = __builtin_amdgcn_mfma_f32_16x16x32_bf16(a[mt], bc[nt], acc[mt][nt], 0, 0, 0);
  }

  // epilogue2: h -> LDS (b1b deferred), then STREAMING store in edge order
  __syncthreads();
#pragma unroll
  for (int nt = 0; nt < 4; ++nt) {
    int col = w * 64 + nt * 16 + lr;
#pragma unroll
    for (int mt = 0; mt < 4; ++mt)
#pragma unroll
      for (int j = 0; j < 4; ++j)
        As[(mt * 16 + lk * 4 + j) * LDA + col] = f2bf(acc[mt][nt][j]);
  }
  __syncthreads();
  for (int i = t; i < 64 * 32; i += 256) {
    int row = i >> 5, g = i & 31;
    us8 v = *(const us8*)(&As[row * LDA + g * 8]);
    *(us8*)(hsort + ((size_t)(e0 + row)) * 256 + g * 8) = v;
  }
}

#define LDN 392  // 384 + 8 pad

// 64 nodes/block, 4 waves. Gather h rows via eid (CSR), f32 accum, then MLP2.
__global__ __launch_bounds__(256, 3) void node_mlp_kernel(
    const float* __restrict__ x, const unsigned short* __restrict__ hsort,
    const int* __restrict__ startA, const int* __restrict__ eid,
    const float* __restrict__ b1b, const float* __restrict__ b2a,
    const float* __restrict__ b2b,
    const unsigned short* __restrict__ w2aP, const unsigned short* __restrict__ w2bP,
    float* __restrict__ out, int N) {
  __shared__ __align__(16) unsigned short As[64 * LDN];
  const int t = threadIdx.x;
  const int n0 = blockIdx.x * 64;

  const int w = t >> 6, l = t & 63;
  const int lr = l & 15, lk = l >> 4;
  const unsigned short* B1 = w2aP + (size_t)(w * 48) * 512 + (size_t)l * 8;
  const unsigned short* B2 = w2bP + (size_t)(w * 16) * 512 + (size_t)l * 8;

  short8 bA[4], bB[4];
#pragma unroll
  for (int n = 0; n < 4; ++n) bA[n] = *(const short8*)(B1 + n * 6144);

  // stage x part: cols [0,128)
  for (int idx = t; idx < 64 * 32; idx += 256) {
    int nn = idx >> 5, c4 = idx & 31;
    int node = n0 + nn;
    fvec4 v = {0.f, 0.f, 0.f, 0.f};
    if (node < N) v = *(const fvec4*)(x + (size_t)node * 128 + c4 * 4);
    us4 o;
    o.x = f2bf(v.x); o.y = f2bf(v.y); o.z = f2bf(v.z); o.w = f2bf(v.w);
    *(us4*)(&As[nn * LDN + c4 * 4]) = o;
  }

  // gather mean via eid: wave w -> nodes [16w,16w+16); lane covers 8 cols (16B),
  // two rows in flight via lane half (l>>5); merge with shfl_xor(32).
  {
    const int c = l & 31;
    const int h = l >> 5;
    float bias[8];
#pragma unroll
    for (int i = 0; i < 8; ++i) bias[i] = b1b[c * 8 + i];

    for (int k = 0; k < 16; ++k) {
      int nn = w * 16 + k;
      int node = n0 + nn;
      float sum[8] = {0.f, 0.f, 0.f, 0.f, 0.f, 0.f, 0.f, 0.f};
      int cn = 0;
      if (node < N) {
        int s = startA[node], e = startA[node + 1];
        cn = e - s;
        for (int r = s + h; r < e; r += 2) {
          int row = eid[r];
          us8 hv = *(const us8*)(hsort + (size_t)row * 256 + c * 8);
#pragma unroll
          for (int i = 0; i < 8; ++i) sum[i] += bf2f(hv[i]);
        }
      }
#pragma unroll
      for (int i = 0; i < 8; ++i) sum[i] += __shfl_xor(sum[i], 32);
      float inv = cn > 0 ? 1.0f / (float)cn : 0.f;
      float gate = cn > 0 ? 1.f : 0.f;
      us8 o;
#pragma unroll
      for (int i = 0; i < 8; ++i) o[i] = f2bf(sum[i] * inv + gate * bias[i]);
      if (h == 0) *(us8*)(&As[nn * LDN + 128 + c * 8]) = o;
    }
  }
  __syncthreads();

  const f32x4 zero4 = {0.f, 0.f, 0.f, 0.f};
  f32x4 acc[4][4];
#pragma unroll
  for (int mt = 0; mt < 4; ++mt)
#pragma unroll
    for (int nt = 0; nt < 4; ++nt) acc[mt][nt] = zero4;

  // GEMM1: [64,384] x W2a[384,256]
#pragma unroll
  for (int kt = 0; kt < 12; ++kt) {
    short8* bc = (kt & 1) ? bB : bA;
    short8* bn = (kt & 1) ? bA : bB;
    if (kt < 11) {
#pragma unroll
      for (int n = 0; n < 4; ++n) bn[n] = *(const short8*)(B1 + n * 6144 + (kt + 1) * 512);
    }
    short8 a[4];
#pragma unroll
    for (int mt = 0; mt < 4; ++mt)
      a[mt] = *(const short8*)(&As[(mt * 16 + lr) * LDN + kt * 32 + lk * 8]);
#pragma unroll
    for (int mt = 0; mt < 4; ++mt)
#pragma unroll
      for (int nt = 0; nt < 4; ++nt)
        acc[mt][nt] = __builtin_amdgcn_mfma_f32_16x16x32_bf16(a[mt], bc[nt], acc[mt][nt], 0, 0, 0);
  }

#pragma unroll
  for (int n = 0; n < 2; ++n) bA[n] = *(const short8*)(B2 + n * 4096);

  __syncthreads();

  // epilogue1: bias + ELU -> H (reuse As, stride 264)
#pragma unroll
  for (int nt = 0; nt < 4; ++nt) {
    int col = w * 64 + nt * 16 + lr;
    float bias = b2a[col];
#pragma unroll
    for (int mt = 0; mt < 4; ++mt)
#pragma unroll
      for (int j = 0; j < 4; ++j) {
        float v = elu_f(acc[mt][nt][j] + bias);
        As[(mt * 16 + lk * 4 + j) * 264 + col] = f2bf(v);
      }
  }
  __syncthreads();

  // GEMM2: H[64,256] x W2b[256,128]; wave w owns cols [32w, 32w+32)
  f32x4 acc2[4][2];
#pragma unroll
  for (int mt = 0; mt < 4; ++mt)
#pragma unroll
    for (int nt = 0; nt < 2; ++nt) acc2[mt][nt] = zero4;
#pragma unroll
  for (int kt = 0; kt < 8; ++kt) {
    short8* bc = (kt & 1) ? bB : bA;
    short8* bn = (kt & 1) ? bA : bB;
    if (kt < 7) {
#pragma unroll
      for (int n = 0; n < 2; ++n) bn[n] = *(const short8*)(B2 + n * 4096 + (kt + 1) * 512);
    }
    short8 a[4];
#pragma unroll
    for (int mt = 0; mt < 4; ++mt)
      a[mt] = *(const short8*)(&As[(mt * 16 + lr) * 264 + kt * 32 + lk * 8]);
#pragma unroll
    for (int mt = 0; mt < 4; ++mt)
#pragma unroll
      for (int nt = 0; nt < 2; ++nt)
        acc2[mt][nt] = __builtin_amdgcn_mfma_f32_16x16x32_bf16(a[mt], bc[nt], acc2[mt][nt], 0, 0, 0);
  }

  // epilogue2: bias + store
#pragma unroll
  for (int nt = 0; nt < 2; ++nt) {
    int col = w * 32 + nt * 16 + lr;
    float bias = b2b[col];
#pragma unroll
    for (int mt = 0; mt < 4; ++mt)
#pragma unroll
      for (int j = 0; j < 4; ++j) {
        int node = n0 + mt * 16 + lk * 4 + j;
        if (node < N) out[(size_t)node * 128 + col] = acc2[mt][nt][j] + bias;
      }
  }
}

extern "C" void kernel_launch(void* const* d_in, const int* in_sizes, int n_in,
                              void* d_out, int out_size, void* d_ws, size_t ws_size,
                              hipStream_t stream) {
  const float* x = (const float*)d_in[0];
  const int* ei = (const int*)d_in[1];
  const float* eattr = (const float*)d_in[2];
  const float* W1a = (const float*)d_in[5];
  const float* b1a = (const float*)d_in[6];
  const float* W1b = (const float*)d_in[7];
  const float* b1b = (const float*)d_in[8];
  const float* W2a = (const float*)d_in[9];
  const float* b2a = (const float*)d_in[10];
  const float* W2b = (const float*)d_in[11];
  const float* b2b = (const float*)d_in[12];

  const int N = in_sizes[0] / 128;   // 25000
  const int E = in_sizes[2] / 128;   // 400000

  char* ws = (char*)d_ws;
  unsigned short* hsort = (unsigned short*)ws;          // E*256 bf16, edge order
  size_t off = (size_t)E * 256 * 2;
  int* cntbuf = (int*)(ws + off); off += (size_t)N * 4;
  int* startA = (int*)(ws + off); off += (size_t)(N + 1) * 4;
  int* offs   = (int*)(ws + off); off += (size_t)N * 4;
  int* eid    = (int*)(ws + off); off += (size_t)E * 4;
  off = (off + 255) & ~(size_t)255;
  unsigned short* w1aP = (unsigned short*)(ws + off); off += 256 * 256 * 2;
  unsigned short* w1bP = (unsigned short*)(ws + off); off += 256 * 256 * 2;
  unsigned short* w2aP = (unsigned short*)(ws + off); off += 384 * 256 * 2;
  unsigned short* w2bP = (unsigned short*)(ws + off);

  (void)hipMemsetAsync(cntbuf, 0, (size_t)N * 4, stream);

  pack_all_kernel<<<1024, 256, 0, stream>>>(W1a, W1b, W2a, W2b, w1aP, w1bP, w2aP, w2bP);

  hist_kernel<<<(E + 255) / 256, 256, 0, stream>>>(ei + E, cntbuf, E);
  scan_kernel<<<1, 1024, 0, stream>>>(cntbuf, startA, offs, N, E);
  eid_kernel<<<(E + 255) / 256, 256, 0, stream>>>(ei + E, offs, eid, E);

  edge_mlp_kernel<<<E / 64, 256, 0, stream>>>(x, ei, eattr, b1a, w1aP, w1bP, hsort);

  node_mlp_kernel<<<(N + 63) / 64, 256, 0, stream>>>(x, hsort, startA, eid, b1b, b2a, b2b,
                                                     w2aP, w2bP, (float*)d_out, N);
}

// Round 8
// 416.076 us; speedup vs baseline: 1.1563x; 1.1563x over previous
//
#include <hip/hip_runtime.h>
#include <hip/hip_bf16.h>
#include <stdint.h>

typedef short short8 __attribute__((ext_vector_type(8)));
typedef float f32x4 __attribute__((ext_vector_type(4)));
typedef float fvec4 __attribute__((ext_vector_type(4)));
typedef unsigned short us4 __attribute__((ext_vector_type(4)));
typedef unsigned short us8 __attribute__((ext_vector_type(8)));

// native float->bf16 (RNE): lowers to v_cvt_pk_bf16_f32 on gfx950, ~4x fewer VALU
// ops than hand-rolled bit rounding (learn_hip m240: compiler fuses scalar casts).
static __device__ __forceinline__ unsigned short f2bf(float f) {
  return __bfloat16_as_ushort(__float2bfloat16(f));
}

static __device__ __forceinline__ float bf2f(unsigned short u) {
  union { uint32_t u; float f; } v; v.u = (uint32_t)u << 16;
  return v.f;
}

// fast ELU: __expf -> v_exp_f32. |err| ~1e-7, fine vs 2e-2 threshold.
static __device__ __forceinline__ float elu_f(float v) {
  return v > 0.0f ? v : __expf(v) - 1.0f;
}

// Pack all 4 weight matrices into MFMA B-fragment order (bf16), one launch.
// frag layout: dst[((nt*KT + kt)*64 + lane)*8 + i] = bf16(W[32kt + 8(lane>>4) + i][16nt + (lane&15)])
__global__ void pack_all_kernel(const float* __restrict__ W1a, const float* __restrict__ W1b,
                                const float* __restrict__ W2a, const float* __restrict__ W2b,
                                unsigned short* __restrict__ w1aP, unsigned short* __restrict__ w1bP,
                                unsigned short* __restrict__ w2aP, unsigned short* __restrict__ w2bP) {
  int p = blockIdx.x * blockDim.x + threadIdx.x;
  const float* W; unsigned short* dst; int KT, Nc, q;
  if (p < 65536)       { W = W1a; dst = w1aP; KT = 8;  Nc = 256; q = p; }
  else if (p < 131072) { W = W1b; dst = w1bP; KT = 8;  Nc = 256; q = p - 65536; }
  else if (p < 229376) { W = W2a; dst = w2aP; KT = 12; Nc = 256; q = p - 131072; }
  else                 { W = W2b; dst = w2bP; KT = 8;  Nc = 128; q = p - 229376; }
  int i = q & 7;
  int l = (q >> 3) & 63;
  int rest = q >> 9;
  int kt = rest % KT;
  int nt = rest / KT;
  dst[q] = f2bf(W[(size_t)(kt * 32 + (l >> 4) * 8 + i) * Nc + nt * 16 + (l & 15)]);
}

__global__ void hist_kernel(const int* __restrict__ col_idx, int* __restrict__ cnt, int E) {
  int i = blockIdx.x * blockDim.x + threadIdx.x;
  if (i < E) atomicAdd(&cnt[col_idx[i]], 1);
}

// single-launch scan: each thread serially owns a chunk, one 1024-wide block scan.
__global__ __launch_bounds__(1024) void scan_kernel(const int* __restrict__ cnt,
                                                    int* __restrict__ startA,
                                                    int* __restrict__ offs, int N, int E) {
  __shared__ int partial[1024];
  const int t = threadIdx.x;
  const int chunk = (N + 1023) >> 10;
  const int base = t * chunk;
  int s = 0;
  for (int i = 0; i < chunk; ++i) {
    int idx = base + i;
    if (idx < N) s += cnt[idx];
  }
  partial[t] = s;
  __syncthreads();
  for (int o = 1; o < 1024; o <<= 1) {
    int a = (t >= o) ? partial[t - o] : 0;
    __syncthreads();
    partial[t] += a;
    __syncthreads();
  }
  int run = partial[t] - s;
  for (int i = 0; i < chunk; ++i) {
    int idx = base + i;
    if (idx < N) {
      startA[idx] = run;
      offs[idx] = run;
      run += cnt[idx];
    }
  }
  if (t == 0) startA[N] = E;
}

#define LDA 264  // 256 + 8 pad (bf16 elems); 528B row stride, 16B aligned

// 64 edges/block, 4 waves; wave w owns output cols [64w, 64w+64).
// Rank computed in-kernel (atomicAdd on offs); h scattered to hsort[rank] (CSR slot).
__global__ __launch_bounds__(256, 4) void edge_mlp_kernel(
    const float* __restrict__ x, const int* __restrict__ row_idx,
    const int* __restrict__ col_idx, const float* __restrict__ eattr,
    const float* __restrict__ b1a,
    const unsigned short* __restrict__ w1aP, const unsigned short* __restrict__ w1bP,
    int* __restrict__ offs, unsigned short* __restrict__ hsort) {
  __shared__ __align__(16) unsigned short As[64 * LDA];
  __shared__ int rowi[64];
  __shared__ int aux[64];
  const int t = threadIdx.x;
  const int e0 = blockIdx.x * 64;

  if (t < 64) {
    rowi[t] = row_idx[e0 + t];
    aux[t] = atomicAdd(&offs[col_idx[e0 + t]], 1);
  }

  const int w = t >> 6, l = t & 63;
  const int lr = l & 15, lk = l >> 4;
  const unsigned short* B1 = w1aP + (size_t)(w * 32) * 512 + (size_t)l * 8;
  const unsigned short* B2 = w1bP + (size_t)(w * 32) * 512 + (size_t)l * 8;

  short8 bA[4], bB[4];
#pragma unroll
  for (int n = 0; n < 4; ++n) bA[n] = *(const short8*)(B1 + n * 4096);

  __syncthreads();

  // stage A: [64 edges][256 feats] as bf16 (x[row] | edge_attr)
  for (int idx = t; idx < 64 * 64; idx += 256) {
    int e = idx >> 6, c4 = idx & 63;
    fvec4 v;
    if (c4 < 32)
      v = *(const fvec4*)(x + (size_t)rowi[e] * 128 + c4 * 4);
    else
      v = __builtin_nontemporal_load((const fvec4*)(eattr + (size_t)(e0 + e) * 128 + (c4 - 32) * 4));
    us4 o;
    o.x = f2bf(v.x); o.y = f2bf(v.y); o.z = f2bf(v.z); o.w = f2bf(v.w);
    *(us4*)(&As[e * LDA + c4 * 4]) = o;
  }
  __syncthreads();

  f32x4 acc[4][4];
  const f32x4 zero4 = {0.f, 0.f, 0.f, 0.f};
#pragma unroll
  for (int mt = 0; mt < 4; ++mt)
#pragma unroll
    for (int nt = 0; nt < 4; ++nt) acc[mt][nt] = zero4;

  // GEMM1: [64,256] x W1a[256,256], B double-buffered
#pragma unroll
  for (int kt = 0; kt < 8; ++kt) {
    short8* bc = (kt & 1) ? bB : bA;
    short8* bn = (kt & 1) ? bA : bB;
    if (kt < 7) {
#pragma unroll
      for (int n = 0; n < 4; ++n) bn[n] = *(const short8*)(B1 + n * 4096 + (kt + 1) * 512);
    }
    short8 a[4];
#pragma unroll
    for (int mt = 0; mt < 4; ++mt)
      a[mt] = *(const short8*)(&As[(mt * 16 + lr) * LDA + kt * 32 + lk * 8]);
#pragma unroll
    for (int mt = 0; mt < 4; ++mt)
#pragma unroll
      for (int nt = 0; nt < 4; ++nt)
        acc[mt][nt] = __builtin_amdgcn_mfma_f32_16x16x32_bf16(a[mt], bc[nt], acc[mt][nt], 0, 0, 0);
  }

#pragma unroll
  for (int n = 0; n < 4; ++n) bA[n] = *(const short8*)(B2 + n * 4096);

  __syncthreads();

  // epilogue1: bias + ELU -> bf16 H (reuse As)
#pragma unroll
  for (int nt = 0; nt < 4; ++nt) {
    int col = w * 64 + nt * 16 + lr;
    float bias = b1a[col];
#pragma unroll
    for (int mt = 0; mt < 4; ++mt)
#pragma unroll
      for (int j = 0; j < 4; ++j) {
        float v = elu_f(acc[mt][nt][j] + bias);
        As[(mt * 16 + lk * 4 + j) * LDA + col] = f2bf(v);
      }
  }
  __syncthreads();

  // GEMM2: H[64,256] x W1b[256,256]
#pragma unroll
  for (int mt = 0; mt < 4; ++mt)
#pragma unroll
    for (int nt = 0; nt < 4; ++nt) acc[mt][nt] = zero4;
#pragma unroll
  for (int kt = 0; kt < 8; ++kt) {
    short8* bc = (kt & 1) ? bB : bA;
    short8* bn = (kt & 1) ? bA : bB;
    if (kt < 7) {
#pragma unroll
      for (int n = 0; n < 4; ++n) bn[n] = *(const short8*)(B2 + n * 4096 + (kt + 1) * 512);
    }
    short8 a[4];
#pragma unroll
    for (int mt = 0; mt < 4; ++mt)
      a[mt] = *(const short8*)(&As[(mt * 16 + lr) * LDA + kt * 32 + lk * 8]);
#pragma unroll
    for (int mt = 0; mt < 4; ++mt)
#pragma unroll
      for (int nt = 0; nt < 4; ++nt)
        acc[mt][nt] = __builtin_amdgcn_mfma_f32_16x16x32_bf16(a[mt], bc[nt], acc[mt][nt], 0, 0, 0);
  }

  // epilogue2: h -> LDS (b1b deferred to node kernel), then 16B-row scatter to CSR slot
  __syncthreads();
#pragma unroll
  for (int nt = 0; nt < 4; ++nt) {
    int col = w * 64 + nt * 16 + lr;
#pragma unroll
    for (int mt = 0; mt < 4; ++mt)
#pragma unroll
      for (int j = 0; j < 4; ++j)
        As[(mt * 16 + lk * 4 + j) * LDA + col] = f2bf(acc[mt][nt][j]);
  }
  __syncthreads();
  for (int i = t; i < 64 * 32; i += 256) {
    int row = i >> 5, g = i & 31;
    us8 v = *(const us8*)(&As[row * LDA + g * 8]);
    *(us8*)(hsort + (size_t)aux[row] * 256 + g * 8) = v;
  }
}

#define LDN 392  // 384 + 8 pad

// 64 nodes/block, 4 waves. Gather CONTIGUOUS CSR rows (f32 accum), then MLP2.
__global__ __launch_bounds__(256, 3) void node_mlp_kernel(
    const float* __restrict__ x, const unsigned short* __restrict__ hsort,
    const int* __restrict__ startA, const float* __restrict__ b1b,
    const float* __restrict__ b2a, const float* __restrict__ b2b,
    const unsigned short* __restrict__ w2aP, const unsigned short* __restrict__ w2bP,
    float* __restrict__ out, int N) {
  __shared__ __align__(16) unsigned short As[64 * LDN];
  const int t = threadIdx.x;
  const int n0 = blockIdx.x * 64;

  const int w = t >> 6, l = t & 63;
  const int lr = l & 15, lk = l >> 4;
  const unsigned short* B1 = w2aP + (size_t)(w * 48) * 512 + (size_t)l * 8;
  const unsigned short* B2 = w2bP + (size_t)(w * 16) * 512 + (size_t)l * 8;

  short8 bA[4], bB[4];
#pragma unroll
  for (int n = 0; n < 4; ++n) bA[n] = *(const short8*)(B1 + n * 6144);

  // stage x part: cols [0,128)
  for (int idx = t; idx < 64 * 32; idx += 256) {
    int nn = idx >> 5, c4 = idx & 31;
    int node = n0 + nn;
    fvec4 v = {0.f, 0.f, 0.f, 0.f};
    if (node < N) v = *(const fvec4*)(x + (size_t)node * 128 + c4 * 4);
    us4 o;
    o.x = f2bf(v.x); o.y = f2bf(v.y); o.z = f2bf(v.z); o.w = f2bf(v.w);
    *(us4*)(&As[nn * LDN + c4 * 4]) = o;
  }

  // gather mean: wave w -> nodes [16w,16w+16); lane covers 8 cols (16B loads),
  // two rows in flight via lane half (l>>5); merge with shfl_xor(32).
  {
    const int c = l & 31;
    const int h = l >> 5;
    float bias[8];
#pragma unroll
    for (int i = 0; i < 8; ++i) bias[i] = b1b[c * 8 + i];

    for (int k = 0; k < 16; ++k) {
      int nn = w * 16 + k;
      int node = n0 + nn;
      float sum[8] = {0.f, 0.f, 0.f, 0.f, 0.f, 0.f, 0.f, 0.f};
      int cn = 0;
      if (node < N) {
        int s = startA[node], e = startA[node + 1];
        cn = e - s;
        for (int r = s + h; r < e; r += 2) {
          us8 hv = *(const us8*)(hsort + (size_t)r * 256 + c * 8);
#pragma unroll
          for (int i = 0; i < 8; ++i) sum[i] += bf2f(hv[i]);
        }
      }
#pragma unroll
      for (int i = 0; i < 8; ++i) sum[i] += __shfl_xor(sum[i], 32);
      float inv = cn > 0 ? 1.0f / (float)cn : 0.f;
      float gate = cn > 0 ? 1.f : 0.f;
      us8 o;
#pragma unroll
      for (int i = 0; i < 8; ++i) o[i] = f2bf(sum[i] * inv + gate * bias[i]);
      if (h == 0) *(us8*)(&As[nn * LDN + 128 + c * 8]) = o;
    }
  }
  __syncthreads();

  const f32x4 zero4 = {0.f, 0.f, 0.f, 0.f};
  f32x4 acc[4][4];
#pragma unroll
  for (int mt = 0; mt < 4; ++mt)
#pragma unroll
    for (int nt = 0; nt < 4; ++nt) acc[mt][nt] = zero4;

  // GEMM1: [64,384] x W2a[384,256]
#pragma unroll
  for (int kt = 0; kt < 12; ++kt) {
    short8* bc = (kt & 1) ? bB : bA;
    short8* bn = (kt & 1) ? bA : bB;
    if (kt < 11) {
#pragma unroll
      for (int n = 0; n < 4; ++n) bn[n] = *(const short8*)(B1 + n * 6144 + (kt + 1) * 512);
    }
    short8 a[4];
#pragma unroll
    for (int mt = 0; mt < 4; ++mt)
      a[mt] = *(const short8*)(&As[(mt * 16 + lr) * LDN + kt * 32 + lk * 8]);
#pragma unroll
    for (int mt = 0; mt < 4; ++mt)
#pragma unroll
      for (int nt = 0; nt < 4; ++nt)
        acc[mt][nt] = __builtin_amdgcn_mfma_f32_16x16x32_bf16(a[mt], bc[nt], acc[mt][nt], 0, 0, 0);
  }

#pragma unroll
  for (int n = 0; n < 2; ++n) bA[n] = *(const short8*)(B2 + n * 4096);

  __syncthreads();

  // epilogue1: bias + ELU -> H (reuse As, stride 264)
#pragma unroll
  for (int nt = 0; nt < 4; ++nt) {
    int col = w * 64 + nt * 16 + lr;
    float bias = b2a[col];
#pragma unroll
    for (int mt = 0; mt < 4; ++mt)
#pragma unroll
      for (int j = 0; j < 4; ++j) {
        float v = elu_f(acc[mt][nt][j] + bias);
        As[(mt * 16 + lk * 4 + j) * 264 + col] = f2bf(v);
      }
  }
  __syncthreads();

  // GEMM2: H[64,256] x W2b[256,128]; wave w owns cols [32w, 32w+32)
  f32x4 acc2[4][2];
#pragma unroll
  for (int mt = 0; mt < 4; ++mt)
#pragma unroll
    for (int nt = 0; nt < 2; ++nt) acc2[mt][nt] = zero4;
#pragma unroll
  for (int kt = 0; kt < 8; ++kt) {
    short8* bc = (kt & 1) ? bB : bA;
    short8* bn = (kt & 1) ? bA : bB;
    if (kt < 7) {
#pragma unroll
      for (int n = 0; n < 2; ++n) bn[n] = *(const short8*)(B2 + n * 4096 + (kt + 1) * 512);
    }
    short8 a[4];
#pragma unroll
    for (int mt = 0; mt < 4; ++mt)
      a[mt] = *(const short8*)(&As[(mt * 16 + lr) * 264 + kt * 32 + lk * 8]);
#pragma unroll
    for (int mt = 0; mt < 4; ++mt)
#pragma unroll
      for (int nt = 0; nt < 2; ++nt)
        acc2[mt][nt] = __builtin_amdgcn_mfma_f32_16x16x32_bf16(a[mt], bc[nt], acc2[mt][nt], 0, 0, 0);
  }

  // epilogue2: bias + store
#pragma unroll
  for (int nt = 0; nt < 2; ++nt) {
    int col = w * 32 + nt * 16 + lr;
    float bias = b2b[col];
#pragma unroll
    for (int mt = 0; mt < 4; ++mt)
#pragma unroll
      for (int j = 0; j < 4; ++j) {
        int node = n0 + mt * 16 + lk * 4 + j;
        if (node < N) out[(size_t)node * 128 + col] = acc2[mt][nt][j] + bias;
      }
  }
}

extern "C" void kernel_launch(void* const* d_in, const int* in_sizes, int n_in,
                              void* d_out, int out_size, void* d_ws, size_t ws_size,
                              hipStream_t stream) {
  const float* x = (const float*)d_in[0];
  const int* ei = (const int*)d_in[1];
  const float* eattr = (const float*)d_in[2];
  const float* W1a = (const float*)d_in[5];
  const float* b1a = (const float*)d_in[6];
  const float* W1b = (const float*)d_in[7];
  const float* b1b = (const float*)d_in[8];
  const float* W2a = (const float*)d_in[9];
  const float* b2a = (const float*)d_in[10];
  const float* W2b = (const float*)d_in[11];
  const float* b2b = (const float*)d_in[12];

  const int N = in_sizes[0] / 128;   // 25000
  const int E = in_sizes[2] / 128;   // 400000

  char* ws = (char*)d_ws;
  unsigned short* hsort = (unsigned short*)ws;          // E*256 bf16, CSR-slot order
  size_t off = (size_t)E * 256 * 2;
  int* cntbuf = (int*)(ws + off); off += (size_t)N * 4;
  int* startA = (int*)(ws + off); off += (size_t)(N + 1) * 4;
  int* offs   = (int*)(ws + off); off += (size_t)N * 4;
  off = (off + 255) & ~(size_t)255;
  unsigned short* w1aP = (unsigned short*)(ws + off); off += 256 * 256 * 2;
  unsigned short* w1bP = (unsigned short*)(ws + off); off += 256 * 256 * 2;
  unsigned short* w2aP = (unsigned short*)(ws + off); off += 384 * 256 * 2;
  unsigned short* w2bP = (unsigned short*)(ws + off);

  (void)hipMemsetAsync(cntbuf, 0, (size_t)N * 4, stream);

  pack_all_kernel<<<1024, 256, 0, stream>>>(W1a, W1b, W2a, W2b, w1aP, w1bP, w2aP, w2bP);

  hist_kernel<<<(E + 255) / 256, 256, 0, stream>>>(ei + E, cntbuf, E);
  scan_kernel<<<1, 1024, 0, stream>>>(cntbuf, startA, offs, N, E);

  edge_mlp_kernel<<<E / 64, 256, 0, stream>>>(x, ei, ei + E, eattr, b1a, w1aP, w1bP,
                                              offs, hsort);

  node_mlp_kernel<<<(N + 63) / 64, 256, 0, stream>>>(x, hsort, startA, b1b, b2a, b2b,
                                                     w2aP, w2bP, (float*)d_out, N);
}

// Round 9
// 357.492 us; speedup vs baseline: 1.3458x; 1.1639x over previous
//
#include <hip/hip_runtime.h>
#include <hip/hip_bf16.h>
#include <stdint.h>

typedef short short8 __attribute__((ext_vector_type(8)));
typedef float f32x4 __attribute__((ext_vector_type(4)));
typedef float fvec4 __attribute__((ext_vector_type(4)));
typedef unsigned short us4 __attribute__((ext_vector_type(4)));

// native float->bf16 (RNE)
static __device__ __forceinline__ unsigned short f2bf(float f) {
  return __bfloat16_as_ushort(__float2bfloat16(f));
}

static __device__ __forceinline__ float bf2f(unsigned short u) {
  union { uint32_t u; float f; } v; v.u = (uint32_t)u << 16;
  return v.f;
}

// fast ELU: __expf -> v_exp_f32. |err| ~1e-7, fine vs 2e-2 threshold.
static __device__ __forceinline__ float elu_f(float v) {
  return v > 0.0f ? v : __expf(v) - 1.0f;
}

// Pack all 4 weight matrices into MFMA B-fragment order (bf16), one launch.
__global__ void pack_all_kernel(const float* __restrict__ W1a, const float* __restrict__ W1b,
                                const float* __restrict__ W2a, const float* __restrict__ W2b,
                                unsigned short* __restrict__ w1aP, unsigned short* __restrict__ w1bP,
                                unsigned short* __restrict__ w2aP, unsigned short* __restrict__ w2bP) {
  int p = blockIdx.x * blockDim.x + threadIdx.x;
  const float* W; unsigned short* dst; int KT, Nc, q;
  if (p < 65536)       { W = W1a; dst = w1aP; KT = 8;  Nc = 256; q = p; }
  else if (p < 131072) { W = W1b; dst = w1bP; KT = 8;  Nc = 256; q = p - 65536; }
  else if (p < 229376) { W = W2a; dst = w2aP; KT = 12; Nc = 256; q = p - 131072; }
  else                 { W = W2b; dst = w2bP; KT = 8;  Nc = 128; q = p - 229376; }
  int i = q & 7;
  int l = (q >> 3) & 63;
  int rest = q >> 9;
  int kt = rest % KT;
  int nt = rest / KT;
  dst[q] = f2bf(W[(size_t)(kt * 32 + (l >> 4) * 8 + i) * Nc + nt * 16 + (l & 15)]);
}

__global__ void hist_kernel(const int* __restrict__ col_idx, int* __restrict__ cnt, int E) {
  int i = blockIdx.x * blockDim.x + threadIdx.x;
  if (i < E) atomicAdd(&cnt[col_idx[i]], 1);
}

// single-launch scan: each thread serially owns a chunk, one 1024-wide block scan.
__global__ __launch_bounds__(1024) void scan_kernel(const int* __restrict__ cnt,
                                                    int* __restrict__ startA,
                                                    int* __restrict__ offs, int N, int E) {
  __shared__ int partial[1024];
  const int t = threadIdx.x;
  const int chunk = (N + 1023) >> 10;
  const int base = t * chunk;
  int s = 0;
  for (int i = 0; i < chunk; ++i) {
    int idx = base + i;
    if (idx < N) s += cnt[idx];
  }
  partial[t] = s;
  __syncthreads();
  for (int o = 1; o < 1024; o <<= 1) {
    int a = (t >= o) ? partial[t - o] : 0;
    __syncthreads();
    partial[t] += a;
    __syncthreads();
  }
  int run = partial[t] - s;
  for (int i = 0; i < chunk; ++i) {
    int idx = base + i;
    if (idx < N) {
      startA[idx] = run;
      offs[idx] = run;
      run += cnt[idx];
    }
  }
  if (t == 0) startA[N] = E;
}

// dst-sorted edge list: eid[csr_slot] = edge
__global__ void eid_kernel(const int* __restrict__ col_idx, int* __restrict__ offs,
                           int* __restrict__ eid, int E) {
  int i = blockIdx.x * blockDim.x + threadIdx.x;
  if (i < E) eid[atomicAdd(&offs[col_idx[i]], 1)] = i;
}

#define LDA 264  // 256 + 8 pad (bf16 elems); 528B row stride, 16B aligned

// 64 dst-sorted CSR slots per block, 4 waves; wave w owns output cols [64w, 64w+64).
// After GEMM2: in-LDS segmented sum over equal-dst runs -> f32 atomicAdd into agg.
// NO per-edge h materialization in HBM.
__global__ __launch_bounds__(256, 4) void edge_mlp_kernel(
    const float* __restrict__ x, const int* __restrict__ row_idx,
    const int* __restrict__ col_idx, const float* __restrict__ eattr,
    const float* __restrict__ b1a,
    const unsigned short* __restrict__ w1aP, const unsigned short* __restrict__ w1bP,
    const int* __restrict__ eid, float* __restrict__ agg) {
  __shared__ __align__(16) unsigned short As[64 * LDA];
  __shared__ int rowi[64];
  __shared__ int eidx[64];
  __shared__ int dsts[64];
  const int t = threadIdx.x;
  const int e0 = blockIdx.x * 64;

  if (t < 64) {
    int e = eid[e0 + t];
    eidx[t] = e;
    rowi[t] = row_idx[e];
    dsts[t] = col_idx[e];  // non-decreasing across the tile by CSR construction
  }

  const int w = t >> 6, l = t & 63;
  const int lr = l & 15, lk = l >> 4;
  const unsigned short* B1 = w1aP + (size_t)(w * 32) * 512 + (size_t)l * 8;
  const unsigned short* B2 = w1bP + (size_t)(w * 32) * 512 + (size_t)l * 8;

  short8 bA[4], bB[4];
#pragma unroll
  for (int n = 0; n < 4; ++n) bA[n] = *(const short8*)(B1 + n * 4096);

  __syncthreads();

  // stage A: [64 slots][256 feats] as bf16 (x[row[eid]] | edge_attr[eid])
  for (int idx = t; idx < 64 * 64; idx += 256) {
    int e = idx >> 6, c4 = idx & 63;
    fvec4 v;
    if (c4 < 32)
      v = *(const fvec4*)(x + (size_t)rowi[e] * 128 + c4 * 4);
    else
      v = __builtin_nontemporal_load((const fvec4*)(eattr + (size_t)eidx[e] * 128 + (c4 - 32) * 4));
    us4 o;
    o.x = f2bf(v.x); o.y = f2bf(v.y); o.z = f2bf(v.z); o.w = f2bf(v.w);
    *(us4*)(&As[e * LDA + c4 * 4]) = o;
  }
  __syncthreads();

  f32x4 acc[4][4];
  const f32x4 zero4 = {0.f, 0.f, 0.f, 0.f};
#pragma unroll
  for (int mt = 0; mt < 4; ++mt)
#pragma unroll
    for (int nt = 0; nt < 4; ++nt) acc[mt][nt] = zero4;

  // GEMM1: [64,256] x W1a[256,256], B double-buffered
#pragma unroll
  for (int kt = 0; kt < 8; ++kt) {
    short8* bc = (kt & 1) ? bB : bA;
    short8* bn = (kt & 1) ? bA : bB;
    if (kt < 7) {
#pragma unroll
      for (int n = 0; n < 4; ++n) bn[n] = *(const short8*)(B1 + n * 4096 + (kt + 1) * 512);
    }
    short8 a[4];
#pragma unroll
    for (int mt = 0; mt < 4; ++mt)
      a[mt] = *(const short8*)(&As[(mt * 16 + lr) * LDA + kt * 32 + lk * 8]);
#pragma unroll
    for (int mt = 0; mt < 4; ++mt)
#pragma unroll
      for (int nt = 0; nt < 4; ++nt)
        acc[mt][nt] = __builtin_amdgcn_mfma_f32_16x16x32_bf16(a[mt], bc[nt], acc[mt][nt], 0, 0, 0);
  }

#pragma unroll
  for (int n = 0; n < 4; ++n) bA[n] = *(const short8*)(B2 + n * 4096);

  __syncthreads();

  // epilogue1: bias + ELU -> bf16 H (reuse As)
#pragma unroll
  for (int nt = 0; nt < 4; ++nt) {
    int col = w * 64 + nt * 16 + lr;
    float bias = b1a[col];
#pragma unroll
    for (int mt = 0; mt < 4; ++mt)
#pragma unroll
      for (int j = 0; j < 4; ++j) {
        float v = elu_f(acc[mt][nt][j] + bias);
        As[(mt * 16 + lk * 4 + j) * LDA + col] = f2bf(v);
      }
  }
  __syncthreads();

  // GEMM2: H[64,256] x W1b[256,256]
#pragma unroll
  for (int mt = 0; mt < 4; ++mt)
#pragma unroll
    for (int nt = 0; nt < 4; ++nt) acc[mt][nt] = zero4;
#pragma unroll
  for (int kt = 0; kt < 8; ++kt) {
    short8* bc = (kt & 1) ? bB : bA;
    short8* bn = (kt & 1) ? bA : bB;
    if (kt < 7) {
#pragma unroll
      for (int n = 0; n < 4; ++n) bn[n] = *(const short8*)(B2 + n * 4096 + (kt + 1) * 512);
    }
    short8 a[4];
#pragma unroll
    for (int mt = 0; mt < 4; ++mt)
      a[mt] = *(const short8*)(&As[(mt * 16 + lr) * LDA + kt * 32 + lk * 8]);
#pragma unroll
    for (int mt = 0; mt < 4; ++mt)
#pragma unroll
      for (int nt = 0; nt < 4; ++nt)
        acc[mt][nt] = __builtin_amdgcn_mfma_f32_16x16x32_bf16(a[mt], bc[nt], acc[mt][nt], 0, 0, 0);
  }

  // epilogue2: h -> LDS bf16 (b1b deferred to node kernel: mean(h+b)==mean(h)+b)
  __syncthreads();
#pragma unroll
  for (int nt = 0; nt < 4; ++nt) {
    int col = w * 64 + nt * 16 + lr;
#pragma unroll
    for (int mt = 0; mt < 4; ++mt)
#pragma unroll
      for (int j = 0; j < 4; ++j)
        As[(mt * 16 + lk * 4 + j) * LDA + col] = f2bf(acc[mt][nt][j]);
  }
  __syncthreads();

  // segmented reduction: thread t owns column t; dst runs are contiguous.
  // Uniform branch (dsts broadcast from LDS). ~4-5 segment flushes per block,
  // each flush = 256 threads x 1 f32 atomic = 1KB coalesced.
  {
    const int col = t;
    float run = 0.f;
    int prev = dsts[0];
#pragma unroll 8
    for (int r = 0; r < 64; ++r) {
      int d = dsts[r];
      if (d != prev) {
        atomicAdd(&agg[(size_t)prev * 256 + col], run);
        run = 0.f;
        prev = d;
      }
      run += bf2f(As[r * LDA + col]);
    }
    atomicAdd(&agg[(size_t)prev * 256 + col], run);
  }
}

#define LDN 392  // 384 + 8 pad

// 64 nodes/block, 4 waves. agg f32 (already summed) -> mean + b1b -> MLP2.
__global__ __launch_bounds__(256, 3) void node_mlp_kernel(
    const float* __restrict__ x, const float* __restrict__ agg,
    const int* __restrict__ startA, const float* __restrict__ b1b,
    const float* __restrict__ b2a, const float* __restrict__ b2b,
    const unsigned short* __restrict__ w2aP, const unsigned short* __restrict__ w2bP,
    float* __restrict__ out, int N) {
  __shared__ __align__(16) unsigned short As[64 * LDN];
  const int t = threadIdx.x;
  const int n0 = blockIdx.x * 64;

  const int w = t >> 6, l = t & 63;
  const int lr = l & 15, lk = l >> 4;
  const unsigned short* B1 = w2aP + (size_t)(w * 48) * 512 + (size_t)l * 8;
  const unsigned short* B2 = w2bP + (size_t)(w * 16) * 512 + (size_t)l * 8;

  short8 bA[4], bB[4];
#pragma unroll
  for (int n = 0; n < 4; ++n) bA[n] = *(const short8*)(B1 + n * 6144);

  // stage x part: cols [0,128)
  for (int idx = t; idx < 64 * 32; idx += 256) {
    int nn = idx >> 5, c4 = idx & 31;
    int node = n0 + nn;
    fvec4 v = {0.f, 0.f, 0.f, 0.f};
    if (node < N) v = *(const fvec4*)(x + (size_t)node * 128 + c4 * 4);
    us4 o;
    o.x = f2bf(v.x); o.y = f2bf(v.y); o.z = f2bf(v.z); o.w = f2bf(v.w);
    *(us4*)(&As[nn * LDN + c4 * 4]) = o;
  }

  // stage agg part: cols [128,384) = agg[node]/cnt + b1b (gated)
  for (int idx = t; idx < 64 * 64; idx += 256) {
    int nn = idx >> 6, c4 = idx & 63;
    int node = n0 + nn;
    fvec4 v = {0.f, 0.f, 0.f, 0.f};
    if (node < N) {
      int cn = startA[node + 1] - startA[node];
      float inv = cn > 0 ? 1.0f / (float)cn : 0.f;
      float g = cn > 0 ? 1.f : 0.f;
      fvec4 a = *(const fvec4*)(agg + (size_t)node * 256 + c4 * 4);
      fvec4 bb = *(const fvec4*)(b1b + c4 * 4);
      v.x = a.x * inv + g * bb.x;
      v.y = a.y * inv + g * bb.y;
      v.z = a.z * inv + g * bb.z;
      v.w = a.w * inv + g * bb.w;
    }
    us4 o;
    o.x = f2bf(v.x); o.y = f2bf(v.y); o.z = f2bf(v.z); o.w = f2bf(v.w);
    *(us4*)(&As[nn * LDN + 128 + c4 * 4]) = o;
  }
  __syncthreads();

  const f32x4 zero4 = {0.f, 0.f, 0.f, 0.f};
  f32x4 acc[4][4];
#pragma unroll
  for (int mt = 0; mt < 4; ++mt)
#pragma unroll
    for (int nt = 0; nt < 4; ++nt) acc[mt][nt] = zero4;

  // GEMM1: [64,384] x W2a[384,256]
#pragma unroll
  for (int kt = 0; kt < 12; ++kt) {
    short8* bc = (kt & 1) ? bB : bA;
    short8* bn = (kt & 1) ? bA : bB;
    if (kt < 11) {
#pragma unroll
      for (int n = 0; n < 4; ++n) bn[n] = *(const short8*)(B1 + n * 6144 + (kt + 1) * 512);
    }
    short8 a[4];
#pragma unroll
    for (int mt = 0; mt < 4; ++mt)
      a[mt] = *(const short8*)(&As[(mt * 16 + lr) * LDN + kt * 32 + lk * 8]);
#pragma unroll
    for (int mt = 0; mt < 4; ++mt)
#pragma unroll
      for (int nt = 0; nt < 4; ++nt)
        acc[mt][nt] = __builtin_amdgcn_mfma_f32_16x16x32_bf16(a[mt], bc[nt], acc[mt][nt], 0, 0, 0);
  }

#pragma unroll
  for (int n = 0; n < 2; ++n) bA[n] = *(const short8*)(B2 + n * 4096);

  __syncthreads();

  // epilogue1: bias + ELU -> H (reuse As, stride 264)
#pragma unroll
  for (int nt = 0; nt < 4; ++nt) {
    int col = w * 64 + nt * 16 + lr;
    float bias = b2a[col];
#pragma unroll
    for (int mt = 0; mt < 4; ++mt)
#pragma unroll
      for (int j = 0; j < 4; ++j) {
        float v = elu_f(acc[mt][nt][j] + bias);
        As[(mt * 16 + lk * 4 + j) * 264 + col] = f2bf(v);
      }
  }
  __syncthreads();

  // GEMM2: H[64,256] x W2b[256,128]; wave w owns cols [32w, 32w+32)
  f32x4 acc2[4][2];
#pragma unroll
  for (int mt = 0; mt < 4; ++mt)
#pragma unroll
    for (int nt = 0; nt < 2; ++nt) acc2[mt][nt] = zero4;
#pragma unroll
  for (int kt = 0; kt < 8; ++kt) {
    short8* bc = (kt & 1) ? bB : bA;
    short8* bn = (kt & 1) ? bA : bB;
    if (kt < 7) {
#pragma unroll
      for (int n = 0; n < 2; ++n) bn[n] = *(const short8*)(B2 + n * 4096 + (kt + 1) * 512);
    }
    short8 a[4];
#pragma unroll
    for (int mt = 0; mt < 4; ++mt)
      a[mt] = *(const short8*)(&As[(mt * 16 + lr) * 264 + kt * 32 + lk * 8]);
#pragma unroll
    for (int mt = 0; mt < 4; ++mt)
#pragma unroll
      for (int nt = 0; nt < 2; ++nt)
        acc2[mt][nt] = __builtin_amdgcn_mfma_f32_16x16x32_bf16(a[mt], bc[nt], acc2[mt][nt], 0, 0, 0);
  }

  // epilogue2: bias + store
#pragma unroll
  for (int nt = 0; nt < 2; ++nt) {
    int col = w * 32 + nt * 16 + lr;
    float bias = b2b[col];
#pragma unroll
    for (int mt = 0; mt < 4; ++mt)
#pragma unroll
      for (int j = 0; j < 4; ++j) {
        int node = n0 + mt * 16 + lk * 4 + j;
        if (node < N) out[(size_t)node * 128 + col] = acc2[mt][nt][j] + bias;
      }
  }
}

extern "C" void kernel_launch(void* const* d_in, const int* in_sizes, int n_in,
                              void* d_out, int out_size, void* d_ws, size_t ws_size,
                              hipStream_t stream) {
  const float* x = (const float*)d_in[0];
  const int* ei = (const int*)d_in[1];
  const float* eattr = (const float*)d_in[2];
  const float* W1a = (const float*)d_in[5];
  const float* b1a = (const float*)d_in[6];
  const float* W1b = (const float*)d_in[7];
  const float* b1b = (const float*)d_in[8];
  const float* W2a = (const float*)d_in[9];
  const float* b2a = (const float*)d_in[10];
  const float* W2b = (const float*)d_in[11];
  const float* b2b = (const float*)d_in[12];

  const int N = in_sizes[0] / 128;   // 25000
  const int E = in_sizes[2] / 128;   // 400000

  char* ws = (char*)d_ws;
  float* agg = (float*)ws;                              // N*256 f32 (atomic sum target)
  size_t off = (size_t)N * 256 * 4;
  int* cntbuf = (int*)(ws + off); off += (size_t)N * 4;
  int* startA = (int*)(ws + off); off += (size_t)(N + 1) * 4;
  int* offs   = (int*)(ws + off); off += (size_t)N * 4;
  int* eid    = (int*)(ws + off); off += (size_t)E * 4;
  off = (off + 255) & ~(size_t)255;
  unsigned short* w1aP = (unsigned short*)(ws + off); off += 256 * 256 * 2;
  unsigned short* w1bP = (unsigned short*)(ws + off); off += 256 * 256 * 2;
  unsigned short* w2aP = (unsigned short*)(ws + off); off += 384 * 256 * 2;
  unsigned short* w2bP = (unsigned short*)(ws + off);

  // zero agg (f32 atomic target) + cntbuf in one contiguous memset
  (void)hipMemsetAsync(ws, 0, (size_t)N * 256 * 4 + (size_t)N * 4, stream);

  pack_all_kernel<<<1024, 256, 0, stream>>>(W1a, W1b, W2a, W2b, w1aP, w1bP, w2aP, w2bP);

  hist_kernel<<<(E + 255) / 256, 256, 0, stream>>>(ei + E, cntbuf, E);
  scan_kernel<<<1, 1024, 0, stream>>>(cntbuf, startA, offs, N, E);
  eid_kernel<<<(E + 255) / 256, 256, 0, stream>>>(ei + E, offs, eid, E);

  edge_mlp_kernel<<<E / 64, 256, 0, stream>>>(x, ei, ei + E, eattr, b1a, w1aP, w1bP,
                                              eid, agg);

  node_mlp_kernel<<<(N + 63) / 64, 256, 0, stream>>>(x, agg, startA, b1b, b2a, b2b,
                                                     w2aP, w2bP, (float*)d_out, N);
}

// Round 10
// 273.620 us; speedup vs baseline: 1.7584x; 1.3065x over previous
//
#include <hip/hip_runtime.h>
#include <hip/hip_bf16.h>
#include <stdint.h>

typedef short short8 __attribute__((ext_vector_type(8)));
typedef float f32x4 __attribute__((ext_vector_type(4)));
typedef float fvec4 __attribute__((ext_vector_type(4)));
typedef unsigned short us4 __attribute__((ext_vector_type(4)));

// native float->bf16 (RNE)
static __device__ __forceinline__ unsigned short f2bf(float f) {
  return __bfloat16_as_ushort(__float2bfloat16(f));
}

static __device__ __forceinline__ float bf2f(unsigned short u) {
  union { uint32_t u; float f; } v; v.u = (uint32_t)u << 16;
  return v.f;
}

// fast ELU: __expf -> v_exp_f32. |err| ~1e-7, fine vs 2e-2 threshold.
static __device__ __forceinline__ float elu_f(float v) {
  return v > 0.0f ? v : __expf(v) - 1.0f;
}

// Pack all 4 weight matrices into MFMA B-fragment order (bf16), one launch.
__global__ void pack_all_kernel(const float* __restrict__ W1a, const float* __restrict__ W1b,
                                const float* __restrict__ W2a, const float* __restrict__ W2b,
                                unsigned short* __restrict__ w1aP, unsigned short* __restrict__ w1bP,
                                unsigned short* __restrict__ w2aP, unsigned short* __restrict__ w2bP) {
  int p = blockIdx.x * blockDim.x + threadIdx.x;
  const float* W; unsigned short* dst; int KT, Nc, q;
  if (p < 65536)       { W = W1a; dst = w1aP; KT = 8;  Nc = 256; q = p; }
  else if (p < 131072) { W = W1b; dst = w1bP; KT = 8;  Nc = 256; q = p - 65536; }
  else if (p < 229376) { W = W2a; dst = w2aP; KT = 12; Nc = 256; q = p - 131072; }
  else                 { W = W2b; dst = w2bP; KT = 8;  Nc = 128; q = p - 229376; }
  int i = q & 7;
  int l = (q >> 3) & 63;
  int rest = q >> 9;
  int kt = rest % KT;
  int nt = rest / KT;
  dst[q] = f2bf(W[(size_t)(kt * 32 + (l >> 4) * 8 + i) * Nc + nt * 16 + (l & 15)]);
}

__global__ void hist_kernel(const int* __restrict__ col_idx, int* __restrict__ cnt, int E) {
  int i = blockIdx.x * blockDim.x + threadIdx.x;
  if (i < E) atomicAdd(&cnt[col_idx[i]], 1);
}

// single-launch scan: each thread serially owns a chunk, one 1024-wide block scan.
__global__ __launch_bounds__(1024) void scan_kernel(const int* __restrict__ cnt,
                                                    int* __restrict__ startA,
                                                    int* __restrict__ offs, int N, int E) {
  __shared__ int partial[1024];
  const int t = threadIdx.x;
  const int chunk = (N + 1023) >> 10;
  const int base = t * chunk;
  int s = 0;
  for (int i = 0; i < chunk; ++i) {
    int idx = base + i;
    if (idx < N) s += cnt[idx];
  }
  partial[t] = s;
  __syncthreads();
  for (int o = 1; o < 1024; o <<= 1) {
    int a = (t >= o) ? partial[t - o] : 0;
    __syncthreads();
    partial[t] += a;
    __syncthreads();
  }
  int run = partial[t] - s;
  for (int i = 0; i < chunk; ++i) {
    int idx = base + i;
    if (idx < N) {
      startA[idx] = run;
      offs[idx] = run;
      run += cnt[idx];
    }
  }
  if (t == 0) startA[N] = E;
}

// dst-sorted edge list: eid[csr_slot] = edge
__global__ void eid_kernel(const int* __restrict__ col_idx, int* __restrict__ offs,
                           int* __restrict__ eid, int E) {
  int i = blockIdx.x * blockDim.x + threadIdx.x;
  if (i < E) eid[atomicAdd(&offs[col_idx[i]], 1)] = i;
}

#define LDA 264  // 256 + 8 pad (bf16 elems); 528B row stride, 16B aligned

// 64 dst-sorted CSR slots/block, 4 waves; wave w owns output cols [64w,64w+64).
// ONLY GEMM1 + ELU here: sum_e(elu(h1) @ W1b) == (sum_e elu(h1)) @ W1b, so W1b
// is applied post-mean in the node kernel. Segmented reduce of elu(h1) -> agg:
// interior segments (dst fully inside tile) are PLAIN STORES; only the 2
// boundary segments per tile need atomics (~3.2M vs 8M).
__global__ __launch_bounds__(256, 4) void edge_mlp_kernel(
    const float* __restrict__ x, const int* __restrict__ row_idx,
    const int* __restrict__ col_idx, const float* __restrict__ eattr,
    const float* __restrict__ b1a,
    const unsigned short* __restrict__ w1aP,
    const int* __restrict__ eid, float* __restrict__ agg) {
  __shared__ __align__(16) unsigned short As[64 * LDA];
  __shared__ int rowi[64];
  __shared__ int eidx[64];
  __shared__ int dsts[64];
  const int t = threadIdx.x;
  const int e0 = blockIdx.x * 64;

  if (t < 64) {
    int e = eid[e0 + t];
    eidx[t] = e;
    rowi[t] = row_idx[e];
    dsts[t] = col_idx[e];  // non-decreasing across the tile (CSR order)
  }

  const int w = t >> 6, l = t & 63;
  const int lr = l & 15, lk = l >> 4;
  const unsigned short* B1 = w1aP + (size_t)(w * 32) * 512 + (size_t)l * 8;

  short8 bA[4], bB[4];
#pragma unroll
  for (int n = 0; n < 4; ++n) bA[n] = *(const short8*)(B1 + n * 4096);

  __syncthreads();

  // stage A: [64 slots][256 feats] as bf16 (x[row[eid]] | edge_attr[eid])
  for (int idx = t; idx < 64 * 64; idx += 256) {
    int e = idx >> 6, c4 = idx & 63;
    fvec4 v;
    if (c4 < 32)
      v = *(const fvec4*)(x + (size_t)rowi[e] * 128 + c4 * 4);
    else
      v = __builtin_nontemporal_load((const fvec4*)(eattr + (size_t)eidx[e] * 128 + (c4 - 32) * 4));
    us4 o;
    o.x = f2bf(v.x); o.y = f2bf(v.y); o.z = f2bf(v.z); o.w = f2bf(v.w);
    *(us4*)(&As[e * LDA + c4 * 4]) = o;
  }
  __syncthreads();

  f32x4 acc[4][4];
  const f32x4 zero4 = {0.f, 0.f, 0.f, 0.f};
#pragma unroll
  for (int mt = 0; mt < 4; ++mt)
#pragma unroll
    for (int nt = 0; nt < 4; ++nt) acc[mt][nt] = zero4;

  // GEMM1: [64,256] x W1a[256,256], B double-buffered
#pragma unroll
  for (int kt = 0; kt < 8; ++kt) {
    short8* bc = (kt & 1) ? bB : bA;
    short8* bn = (kt & 1) ? bA : bB;
    if (kt < 7) {
#pragma unroll
      for (int n = 0; n < 4; ++n) bn[n] = *(const short8*)(B1 + n * 4096 + (kt + 1) * 512);
    }
    short8 a[4];
#pragma unroll
    for (int mt = 0; mt < 4; ++mt)
      a[mt] = *(const short8*)(&As[(mt * 16 + lr) * LDA + kt * 32 + lk * 8]);
#pragma unroll
    for (int mt = 0; mt < 4; ++mt)
#pragma unroll
      for (int nt = 0; nt < 4; ++nt)
        acc[mt][nt] = __builtin_amdgcn_mfma_f32_16x16x32_bf16(a[mt], bc[nt], acc[mt][nt], 0, 0, 0);
  }
  __syncthreads();  // all waves done reading As

  // epilogue: bias + ELU -> bf16 back into As
#pragma unroll
  for (int nt = 0; nt < 4; ++nt) {
    int col = w * 64 + nt * 16 + lr;
    float bias = b1a[col];
#pragma unroll
    for (int mt = 0; mt < 4; ++mt)
#pragma unroll
      for (int j = 0; j < 4; ++j) {
        float v = elu_f(acc[mt][nt][j] + bias);
        As[(mt * 16 + lk * 4 + j) * LDA + col] = f2bf(v);
      }
  }
  __syncthreads();

  // segmented reduction over dst-runs; thread t owns column t.
  {
    const int col = t;
    float run = 0.f;
    int prev = dsts[0];
    int segstart = 0;
#pragma unroll 8
    for (int r = 0; r < 64; ++r) {
      int d = dsts[r];
      if (d != prev) {
        if (segstart == 0)
          atomicAdd(&agg[(size_t)prev * 256 + col], run);
        else
          agg[(size_t)prev * 256 + col] = run;  // interior: sole owner
        run = 0.f;
        prev = d;
        segstart = r;
      }
      run += bf2f(As[r * LDA + col]);
    }
    atomicAdd(&agg[(size_t)prev * 256 + col], run);  // tail touches tile edge
  }
}

#define LDN 392  // 384 + 8 pad

// 64 nodes/block, 4 waves.
// Phase A: magg = agg/cnt -> GEMM x W1b -> u (+b1b, gated).
// Phase B: [x | u] -> MLP2 (GEMM 384->256, ELU, GEMM 256->128).
// Phase A's staging (stride 264) time-shares LDS with phase B's (stride 392).
__global__ __launch_bounds__(256, 3) void node_mlp_kernel(
    const float* __restrict__ x, const float* __restrict__ agg,
    const int* __restrict__ startA, const float* __restrict__ b1b,
    const float* __restrict__ b2a, const float* __restrict__ b2b,
    const unsigned short* __restrict__ w1bP, const unsigned short* __restrict__ w2aP,
    const unsigned short* __restrict__ w2bP,
    float* __restrict__ out, int N) {
  __shared__ __align__(16) unsigned short As[64 * LDN];
  __shared__ float inv64[64];
  const int t = threadIdx.x;
  const int n0 = blockIdx.x * 64;

  const int w = t >> 6, l = t & 63;
  const int lr = l & 15, lk = l >> 4;
  const unsigned short* B0 = w1bP + (size_t)(w * 32) * 512 + (size_t)l * 8;
  const unsigned short* B1 = w2aP + (size_t)(w * 48) * 512 + (size_t)l * 8;
  const unsigned short* B2 = w2bP + (size_t)(w * 16) * 512 + (size_t)l * 8;

  if (t < 64) {
    int node = n0 + t;
    int cn = (node < N) ? (startA[node + 1] - startA[node]) : 0;
    inv64[t] = cn > 0 ? 1.0f / (float)cn : 0.f;
  }

  short8 bA[4], bB[4];
#pragma unroll
  for (int n = 0; n < 4; ++n) bA[n] = *(const short8*)(B0 + n * 4096);

  __syncthreads();  // inv64 ready

  // stage magg: [64][264] bf16 = agg[node]*inv
  for (int idx = t; idx < 64 * 64; idx += 256) {
    int nn = idx >> 6, c4 = idx & 63;
    int node = n0 + nn;
    fvec4 v = {0.f, 0.f, 0.f, 0.f};
    if (node < N) {
      float inv = inv64[nn];
      fvec4 a = *(const fvec4*)(agg + (size_t)node * 256 + c4 * 4);
      v.x = a.x * inv; v.y = a.y * inv; v.z = a.z * inv; v.w = a.w * inv;
    }
    us4 o;
    o.x = f2bf(v.x); o.y = f2bf(v.y); o.z = f2bf(v.z); o.w = f2bf(v.w);
    *(us4*)(&As[nn * 264 + c4 * 4]) = o;
  }
  __syncthreads();

  const f32x4 zero4 = {0.f, 0.f, 0.f, 0.f};
  f32x4 accU[4][4];
#pragma unroll
  for (int mt = 0; mt < 4; ++mt)
#pragma unroll
    for (int nt = 0; nt < 4; ++nt) accU[mt][nt] = zero4;

  // GEMM-u: magg[64,256] x W1b[256,256]
#pragma unroll
  for (int kt = 0; kt < 8; ++kt) {
    short8* bc = (kt & 1) ? bB : bA;
    short8* bn = (kt & 1) ? bA : bB;
    if (kt < 7) {
#pragma unroll
      for (int n = 0; n < 4; ++n) bn[n] = *(const short8*)(B0 + n * 4096 + (kt + 1) * 512);
    }
    short8 a[4];
#pragma unroll
    for (int mt = 0; mt < 4; ++mt)
      a[mt] = *(const short8*)(&As[(mt * 16 + lr) * 264 + kt * 32 + lk * 8]);
#pragma unroll
    for (int mt = 0; mt < 4; ++mt)
#pragma unroll
      for (int nt = 0; nt < 4; ++nt)
        accU[mt][nt] = __builtin_amdgcn_mfma_f32_16x16x32_bf16(a[mt], bc[nt], accU[mt][nt], 0, 0, 0);
  }

  // prefetch W2a kt=0
#pragma unroll
  for (int n = 0; n < 4; ++n) bA[n] = *(const short8*)(B1 + n * 6144);

  __syncthreads();  // magg reads done; As re-purposed at stride 392

  // stage x into cols [0,128) of the [64][392] buffer
  for (int idx = t; idx < 64 * 32; idx += 256) {
    int nn = idx >> 5, c4 = idx & 31;
    int node = n0 + nn;
    fvec4 v = {0.f, 0.f, 0.f, 0.f};
    if (node < N) v = *(const fvec4*)(x + (size_t)node * 128 + c4 * 4);
    us4 o;
    o.x = f2bf(v.x); o.y = f2bf(v.y); o.z = f2bf(v.z); o.w = f2bf(v.w);
    *(us4*)(&As[nn * LDN + c4 * 4]) = o;
  }

  // write u = accU + b1b (gated by cnt>0) into cols [128,384)
#pragma unroll
  for (int nt = 0; nt < 4; ++nt) {
    int col = w * 64 + nt * 16 + lr;
    float bias = b1b[col];
#pragma unroll
    for (int mt = 0; mt < 4; ++mt)
#pragma unroll
      for (int j = 0; j < 4; ++j) {
        int row = mt * 16 + lk * 4 + j;
        float g = inv64[row] > 0.f ? 1.f : 0.f;
        As[row * LDN + 128 + col] = f2bf(accU[mt][nt][j] + g * bias);
      }
  }
  __syncthreads();

  f32x4 acc[4][4];
#pragma unroll
  for (int mt = 0; mt < 4; ++mt)
#pragma unroll
    for (int nt = 0; nt < 4; ++nt) acc[mt][nt] = zero4;

  // MLP2 GEMM1: [64,384] x W2a[384,256]
#pragma unroll
  for (int kt = 0; kt < 12; ++kt) {
    short8* bc = (kt & 1) ? bB : bA;
    short8* bn = (kt & 1) ? bA : bB;
    if (kt < 11) {
#pragma unroll
      for (int n = 0; n < 4; ++n) bn[n] = *(const short8*)(B1 + n * 6144 + (kt + 1) * 512);
    }
    short8 a[4];
#pragma unroll
    for (int mt = 0; mt < 4; ++mt)
      a[mt] = *(const short8*)(&As[(mt * 16 + lr) * LDN + kt * 32 + lk * 8]);
#pragma unroll
    for (int mt = 0; mt < 4; ++mt)
#pragma unroll
      for (int nt = 0; nt < 4; ++nt)
        acc[mt][nt] = __builtin_amdgcn_mfma_f32_16x16x32_bf16(a[mt], bc[nt], acc[mt][nt], 0, 0, 0);
  }

#pragma unroll
  for (int n = 0; n < 2; ++n) bA[n] = *(const short8*)(B2 + n * 4096);

  __syncthreads();

  // epilogue1: bias + ELU -> H (reuse As, stride 264)
#pragma unroll
  for (int nt = 0; nt < 4; ++nt) {
    int col = w * 64 + nt * 16 + lr;
    float bias = b2a[col];
#pragma unroll
    for (int mt = 0; mt < 4; ++mt)
#pragma unroll
      for (int j = 0; j < 4; ++j) {
        float v = elu_f(acc[mt][nt][j] + bias);
        As[(mt * 16 + lk * 4 + j) * 264 + col] = f2bf(v);
      }
  }
  __syncthreads();

  // GEMM2: H[64,256] x W2b[256,128]; wave w owns cols [32w, 32w+32)
  f32x4 acc2[4][2];
#pragma unroll
  for (int mt = 0; mt < 4; ++mt)
#pragma unroll
    for (int nt = 0; nt < 2; ++nt) acc2[mt][nt] = zero4;
#pragma unroll
  for (int kt = 0; kt < 8; ++kt) {
    short8* bc = (kt & 1) ? bB : bA;
    short8* bn = (kt & 1) ? bA : bB;
    if (kt < 7) {
#pragma unroll
      for (int n = 0; n < 2; ++n) bn[n] = *(const short8*)(B2 + n * 4096 + (kt + 1) * 512);
    }
    short8 a[4];
#pragma unroll
    for (int mt = 0; mt < 4; ++mt)
      a[mt] = *(const short8*)(&As[(mt * 16 + lr) * 264 + kt * 32 + lk * 8]);
#pragma unroll
    for (int mt = 0; mt < 4; ++mt)
#pragma unroll
      for (int nt = 0; nt < 2; ++nt)
        acc2[mt][nt] = __builtin_amdgcn_mfma_f32_16x16x32_bf16(a[mt], bc[nt], acc2[mt][nt], 0, 0, 0);
  }

  // epilogue2: bias + store
#pragma unroll
  for (int nt = 0; nt < 2; ++nt) {
    int col = w * 32 + nt * 16 + lr;
    float bias = b2b[col];
#pragma unroll
    for (int mt = 0; mt < 4; ++mt)
#pragma unroll
      for (int j = 0; j < 4; ++j) {
        int node = n0 + mt * 16 + lk * 4 + j;
        if (node < N) out[(size_t)node * 128 + col] = acc2[mt][nt][j] + bias;
      }
  }
}

extern "C" void kernel_launch(void* const* d_in, const int* in_sizes, int n_in,
                              void* d_out, int out_size, void* d_ws, size_t ws_size,
                              hipStream_t stream) {
  const float* x = (const float*)d_in[0];
  const int* ei = (const int*)d_in[1];
  const float* eattr = (const float*)d_in[2];
  const float* W1a = (const float*)d_in[5];
  const float* b1a = (const float*)d_in[6];
  const float* W1b = (const float*)d_in[7];
  const float* b1b = (const float*)d_in[8];
  const float* W2a = (const float*)d_in[9];
  const float* b2a = (const float*)d_in[10];
  const float* W2b = (const float*)d_in[11];
  const float* b2b = (const float*)d_in[12];

  const int N = in_sizes[0] / 128;   // 25000
  const int E = in_sizes[2] / 128;   // 400000

  char* ws = (char*)d_ws;
  float* agg = (float*)ws;                              // N*256 f32 (sum of elu(h1))
  size_t off = (size_t)N * 256 * 4;
  int* cntbuf = (int*)(ws + off); off += (size_t)N * 4;
  int* startA = (int*)(ws + off); off += (size_t)(N + 1) * 4;
  int* offs   = (int*)(ws + off); off += (size_t)N * 4;
  int* eid    = (int*)(ws + off); off += (size_t)E * 4;
  off = (off + 255) & ~(size_t)255;
  unsigned short* w1aP = (unsigned short*)(ws + off); off += 256 * 256 * 2;
  unsigned short* w1bP = (unsigned short*)(ws + off); off += 256 * 256 * 2;
  unsigned short* w2aP = (unsigned short*)(ws + off); off += 384 * 256 * 2;
  unsigned short* w2bP = (unsigned short*)(ws + off);

  // zero agg + cntbuf in one contiguous memset
  (void)hipMemsetAsync(ws, 0, (size_t)N * 256 * 4 + (size_t)N * 4, stream);

  pack_all_kernel<<<1024, 256, 0, stream>>>(W1a, W1b, W2a, W2b, w1aP, w1bP, w2aP, w2bP);

  hist_kernel<<<(E + 255) / 256, 256, 0, stream>>>(ei + E, cntbuf, E);
  scan_kernel<<<1, 1024, 0, stream>>>(cntbuf, startA, offs, N, E);
  eid_kernel<<<(E + 255) / 256, 256, 0, stream>>>(ei + E, offs, eid, E);

  edge_mlp_kernel<<<E / 64, 256, 0, stream>>>(x, ei, ei + E, eattr, b1a, w1aP, eid, agg);

  node_mlp_kernel<<<(N + 63) / 64, 256, 0, stream>>>(x, agg, startA, b1b, b2a, b2b,
                                                     w1bP, w2aP, w2bP, (float*)d_out, N);
}

// Round 12
// 269.853 us; speedup vs baseline: 1.7829x; 1.0140x over previous
//
#include <hip/hip_runtime.h>
#include <hip/hip_bf16.h>
#include <stdint.h>

typedef short short8 __attribute__((ext_vector_type(8)));
typedef float f32x4 __attribute__((ext_vector_type(4)));
typedef float fvec4 __attribute__((ext_vector_type(4)));
typedef unsigned short us4 __attribute__((ext_vector_type(4)));

// native float->bf16 (RNE)
static __device__ __forceinline__ unsigned short f2bf(float f) {
  return __bfloat16_as_ushort(__float2bfloat16(f));
}

static __device__ __forceinline__ float bf2f(unsigned short u) {
  union { uint32_t u; float f; } v; v.u = (uint32_t)u << 16;
  return v.f;
}

// fast ELU: __expf -> v_exp_f32. |err| ~1e-7, fine vs 2e-2 threshold.
static __device__ __forceinline__ float elu_f(float v) {
  return v > 0.0f ? v : __expf(v) - 1.0f;
}

// Fused prep, three block ranges running concurrently:
//   [0, 1024)            : pack all 4 weights into MFMA B-fragment order
//   [1024, 1024+hb)      : histogram dst counts
//   [1024+hb, ...)       : zero agg (N*256 f32) with fvec4 stores
__global__ void prep_kernel(const float* __restrict__ W1a, const float* __restrict__ W1b,
                            const float* __restrict__ W2a, const float* __restrict__ W2b,
                            unsigned short* __restrict__ w1aP, unsigned short* __restrict__ w1bP,
                            unsigned short* __restrict__ w2aP, unsigned short* __restrict__ w2bP,
                            const int* __restrict__ col_idx, int* __restrict__ cnt, int E,
                            float* __restrict__ agg, int aggN, int hb) {
  int b = blockIdx.x;
  if (b < 1024) {
    int p = b * 256 + threadIdx.x;
    const float* W; unsigned short* dst; int KT, Nc, q;
    if (p < 65536)       { W = W1a; dst = w1aP; KT = 8;  Nc = 256; q = p; }
    else if (p < 131072) { W = W1b; dst = w1bP; KT = 8;  Nc = 256; q = p - 65536; }
    else if (p < 229376) { W = W2a; dst = w2aP; KT = 12; Nc = 256; q = p - 131072; }
    else                 { W = W2b; dst = w2bP; KT = 8;  Nc = 128; q = p - 229376; }
    int i = q & 7;
    int l = (q >> 3) & 63;
    int rest = q >> 9;
    int kt = rest % KT;
    int nt = rest / KT;
    dst[q] = f2bf(W[(size_t)(kt * 32 + (l >> 4) * 8 + i) * Nc + nt * 16 + (l & 15)]);
  } else if (b < 1024 + hb) {
    int i = (b - 1024) * 256 + threadIdx.x;
    if (i < E) atomicAdd(&cnt[col_idx[i]], 1);
  } else {
    int idx = (b - 1024 - hb) * 256 + threadIdx.x;  // fvec4 index
    if (idx * 4 < aggN) {
      fvec4 z = {0.f, 0.f, 0.f, 0.f};
      *(fvec4*)(agg + (size_t)idx * 4) = z;
    }
  }
}

// single-launch scan: each thread serially owns a chunk, one 1024-wide block scan.
__global__ __launch_bounds__(1024) void scan_kernel(const int* __restrict__ cnt,
                                                    int* __restrict__ startA,
                                                    int* __restrict__ offs, int N, int E) {
  __shared__ int partial[1024];
  const int t = threadIdx.x;
  const int chunk = (N + 1023) >> 10;
  const int base = t * chunk;
  int s = 0;
  for (int i = 0; i < chunk; ++i) {
    int idx = base + i;
    if (idx < N) s += cnt[idx];
  }
  partial[t] = s;
  __syncthreads();
  for (int o = 1; o < 1024; o <<= 1) {
    int a = (t >= o) ? partial[t - o] : 0;
    __syncthreads();
    partial[t] += a;
    __syncthreads();
  }
  int run = partial[t] - s;
  for (int i = 0; i < chunk; ++i) {
    int idx = base + i;
    if (idx < N) {
      startA[idx] = run;
      offs[idx] = run;
      run += cnt[idx];
    }
  }
  if (t == 0) startA[N] = E;
}

// dst-sorted edge list: eid[csr_slot] = edge
__global__ void eid_kernel(const int* __restrict__ col_idx, int* __restrict__ offs,
                           int* __restrict__ eid, int E) {
  int i = blockIdx.x * blockDim.x + threadIdx.x;
  if (i < E) eid[atomicAdd(&offs[col_idx[i]], 1)] = i;
}

#define LDA 264  // 256 + 8 pad (bf16 elems); 528B row stride, 16B aligned

// 64 dst-sorted CSR slots/block, 4 waves; wave w owns output cols [64w,64w+64).
// GEMM1 + ELU + segmented reduce (W1b applied post-mean in node kernel).
// Interior segments: plain stores (sole owner); first/last segment: atomicAdd.
// [proven: this exact kernel passed full harness incl. post-timing in R10]
__global__ __launch_bounds__(256, 4) void edge_mlp_kernel(
    const float* __restrict__ x, const int* __restrict__ row_idx,
    const int* __restrict__ col_idx, const float* __restrict__ eattr,
    const float* __restrict__ b1a,
    const unsigned short* __restrict__ w1aP,
    const int* __restrict__ eid, float* __restrict__ agg) {
  __shared__ __align__(16) unsigned short As[64 * LDA];
  __shared__ int rowi[64];
  __shared__ int eidx[64];
  __shared__ int dsts[64];
  const int t = threadIdx.x;
  const int e0 = blockIdx.x * 64;

  if (t < 64) {
    int e = eid[e0 + t];
    eidx[t] = e;
    rowi[t] = row_idx[e];
    dsts[t] = col_idx[e];  // non-decreasing across the tile (CSR order)
  }

  const int w = t >> 6, l = t & 63;
  const int lr = l & 15, lk = l >> 4;
  const unsigned short* B1 = w1aP + (size_t)(w * 32) * 512 + (size_t)l * 8;

  short8 bA[4], bB[4];
#pragma unroll
  for (int n = 0; n < 4; ++n) bA[n] = *(const short8*)(B1 + n * 4096);

  __syncthreads();

  // stage A: [64 slots][256 feats] as bf16 (x[row[eid]] | edge_attr[eid])
  for (int idx = t; idx < 64 * 64; idx += 256) {
    int e = idx >> 6, c4 = idx & 63;
    fvec4 v;
    if (c4 < 32)
      v = *(const fvec4*)(x + (size_t)rowi[e] * 128 + c4 * 4);
    else
      v = __builtin_nontemporal_load((const fvec4*)(eattr + (size_t)eidx[e] * 128 + (c4 - 32) * 4));
    us4 o;
    o.x = f2bf(v.x); o.y = f2bf(v.y); o.z = f2bf(v.z); o.w = f2bf(v.w);
    *(us4*)(&As[e * LDA + c4 * 4]) = o;
  }
  __syncthreads();

  f32x4 acc[4][4];
  const f32x4 zero4 = {0.f, 0.f, 0.f, 0.f};
#pragma unroll
  for (int mt = 0; mt < 4; ++mt)
#pragma unroll
    for (int nt = 0; nt < 4; ++nt) acc[mt][nt] = zero4;

  // GEMM1: [64,256] x W1a[256,256], B double-buffered
#pragma unroll
  for (int kt = 0; kt < 8; ++kt) {
    short8* bc = (kt & 1) ? bB : bA;
    short8* bn = (kt & 1) ? bA : bB;
    if (kt < 7) {
#pragma unroll
      for (int n = 0; n < 4; ++n) bn[n] = *(const short8*)(B1 + n * 4096 + (kt + 1) * 512);
    }
    short8 a[4];
#pragma unroll
    for (int mt = 0; mt < 4; ++mt)
      a[mt] = *(const short8*)(&As[(mt * 16 + lr) * LDA + kt * 32 + lk * 8]);
#pragma unroll
    for (int mt = 0; mt < 4; ++mt)
#pragma unroll
      for (int nt = 0; nt < 4; ++nt)
        acc[mt][nt] = __builtin_amdgcn_mfma_f32_16x16x32_bf16(a[mt], bc[nt], acc[mt][nt], 0, 0, 0);
  }
  __syncthreads();  // all waves done reading As

  // epilogue: bias + ELU -> bf16 back into As
#pragma unroll
  for (int nt = 0; nt < 4; ++nt) {
    int col = w * 64 + nt * 16 + lr;
    float bias = b1a[col];
#pragma unroll
    for (int mt = 0; mt < 4; ++mt)
#pragma unroll
      for (int j = 0; j < 4; ++j) {
        float v = elu_f(acc[mt][nt][j] + bias);
        As[(mt * 16 + lk * 4 + j) * LDA + col] = f2bf(v);
      }
  }
  __syncthreads();

  // segmented reduction over dst-runs; thread t owns column t.
  {
    const int col = t;
    float run = 0.f;
    int prev = dsts[0];
    int segstart = 0;
#pragma unroll 8
    for (int r = 0; r < 64; ++r) {
      int d = dsts[r];
      if (d != prev) {
        if (segstart == 0)
          atomicAdd(&agg[(size_t)prev * 256 + col], run);
        else
          agg[(size_t)prev * 256 + col] = run;  // interior: sole owner
        run = 0.f;
        prev = d;
        segstart = r;
      }
      run += bf2f(As[r * LDA + col]);
    }
    atomicAdd(&agg[(size_t)prev * 256 + col], run);  // tail touches tile edge
  }
}

#define LDN 392  // 384 + 8 pad

// 64 nodes/block, 4 waves.
// Phase A: magg = agg/cnt -> GEMM x W1b -> u (+b1b, gated).
// Phase B: [x | u] -> MLP2 (GEMM 384->256, ELU, GEMM 256->128).
// [proven: this exact kernel passed full harness in R10]
__global__ __launch_bounds__(256, 3) void node_mlp_kernel(
    const float* __restrict__ x, const float* __restrict__ agg,
    const int* __restrict__ startA, const float* __restrict__ b1b,
    const float* __restrict__ b2a, const float* __restrict__ b2b,
    const unsigned short* __restrict__ w1bP, const unsigned short* __restrict__ w2aP,
    const unsigned short* __restrict__ w2bP,
    float* __restrict__ out, int N) {
  __shared__ __align__(16) unsigned short As[64 * LDN];
  __shared__ float inv64[64];
  const int t = threadIdx.x;
  const int n0 = blockIdx.x * 64;

  const int w = t >> 6, l = t & 63;
  const int lr = l & 15, lk = l >> 4;
  const unsigned short* B0 = w1bP + (size_t)(w * 32) * 512 + (size_t)l * 8;
  const unsigned short* B1 = w2aP + (size_t)(w * 48) * 512 + (size_t)l * 8;
  const unsigned short* B2 = w2bP + (size_t)(w * 16) * 512 + (size_t)l * 8;

  if (t < 64) {
    int node = n0 + t;
    int cn = (node < N) ? (startA[node + 1] - startA[node]) : 0;
    inv64[t] = cn > 0 ? 1.0f / (float)cn : 0.f;
  }

  short8 bA[4], bB[4];
#pragma unroll
  for (int n = 0; n < 4; ++n) bA[n] = *(const short8*)(B0 + n * 4096);

  __syncthreads();  // inv64 ready

  // stage magg: [64][264] bf16 = agg[node]*inv
  for (int idx = t; idx < 64 * 64; idx += 256) {
    int nn = idx >> 6, c4 = idx & 63;
    int node = n0 + nn;
    fvec4 v = {0.f, 0.f, 0.f, 0.f};
    if (node < N) {
      float inv = inv64[nn];
      fvec4 a = *(const fvec4*)(agg + (size_t)node * 256 + c4 * 4);
      v.x = a.x * inv; v.y = a.y * inv; v.z = a.z * inv; v.w = a.w * inv;
    }
    us4 o;
    o.x = f2bf(v.x); o.y = f2bf(v.y); o.z = f2bf(v.z); o.w = f2bf(v.w);
    *(us4*)(&As[nn * 264 + c4 * 4]) = o;
  }
  __syncthreads();

  const f32x4 zero4 = {0.f, 0.f, 0.f, 0.f};
  f32x4 accU[4][4];
#pragma unroll
  for (int mt = 0; mt < 4; ++mt)
#pragma unroll
    for (int nt = 0; nt < 4; ++nt) accU[mt][nt] = zero4;

  // GEMM-u: magg[64,256] x W1b[256,256]
#pragma unroll
  for (int kt = 0; kt < 8; ++kt) {
    short8* bc = (kt & 1) ? bB : bA;
    short8* bn = (kt & 1) ? bA : bB;
    if (kt < 7) {
#pragma unroll
      for (int n = 0; n < 4; ++n) bn[n] = *(const short8*)(B0 + n * 4096 + (kt + 1) * 512);
    }
    short8 a[4];
#pragma unroll
    for (int mt = 0; mt < 4; ++mt)
      a[mt] = *(const short8*)(&As[(mt * 16 + lr) * 264 + kt * 32 + lk * 8]);
#pragma unroll
    for (int mt = 0; mt < 4; ++mt)
#pragma unroll
      for (int nt = 0; nt < 4; ++nt)
        accU[mt][nt] = __builtin_amdgcn_mfma_f32_16x16x32_bf16(a[mt], bc[nt], accU[mt][nt], 0, 0, 0);
  }

  // prefetch W2a kt=0
#pragma unroll
  for (int n = 0; n < 4; ++n) bA[n] = *(const short8*)(B1 + n * 6144);

  __syncthreads();  // magg reads done; As re-purposed at stride 392

  // stage x into cols [0,128) of the [64][392] buffer
  for (int idx = t; idx < 64 * 32; idx += 256) {
    int nn = idx >> 5, c4 = idx & 31;
    int node = n0 + nn;
    fvec4 v = {0.f, 0.f, 0.f, 0.f};
    if (node < N) v = *(const fvec4*)(x + (size_t)node * 128 + c4 * 4);
    us4 o;
    o.x = f2bf(v.x); o.y = f2bf(v.y); o.z = f2bf(v.z); o.w = f2bf(v.w);
    *(us4*)(&As[nn * LDN + c4 * 4]) = o;
  }

  // write u = accU + b1b (gated by cnt>0) into cols [128,384)
#pragma unroll
  for (int nt = 0; nt < 4; ++nt) {
    int col = w * 64 + nt * 16 + lr;
    float bias = b1b[col];
#pragma unroll
    for (int mt = 0; mt < 4; ++mt)
#pragma unroll
      for (int j = 0; j < 4; ++j) {
        int row = mt * 16 + lk * 4 + j;
        float g = inv64[row] > 0.f ? 1.f : 0.f;
        As[row * LDN + 128 + col] = f2bf(accU[mt][nt][j] + g * bias);
      }
  }
  __syncthreads();

  f32x4 acc[4][4];
#pragma unroll
  for (int mt = 0; mt < 4; ++mt)
#pragma unroll
    for (int nt = 0; nt < 4; ++nt) acc[mt][nt] = zero4;

  // MLP2 GEMM1: [64,384] x W2a[384,256]
#pragma unroll
  for (int kt = 0; kt < 12; ++kt) {
    short8* bc = (kt & 1) ? bB : bA;
    short8* bn = (kt & 1) ? bA : bB;
    if (kt < 11) {
#pragma unroll
      for (int n = 0; n < 4; ++n) bn[n] = *(const short8*)(B1 + n * 6144 + (kt + 1) * 512);
    }
    short8 a[4];
#pragma unroll
    for (int mt = 0; mt < 4; ++mt)
      a[mt] = *(const short8*)(&As[(mt * 16 + lr) * LDN + kt * 32 + lk * 8]);
#pragma unroll
    for (int mt = 0; mt < 4; ++mt)
#pragma unroll
      for (int nt = 0; nt < 4; ++nt)
        acc[mt][nt] = __builtin_amdgcn_mfma_f32_16x16x32_bf16(a[mt], bc[nt], acc[mt][nt], 0, 0, 0);
  }

#pragma unroll
  for (int n = 0; n < 2; ++n) bA[n] = *(const short8*)(B2 + n * 4096);

  __syncthreads();

  // epilogue1: bias + ELU -> H (reuse As, stride 264)
#pragma unroll
  for (int nt = 0; nt < 4; ++nt) {
    int col = w * 64 + nt * 16 + lr;
    float bias = b2a[col];
#pragma unroll
    for (int mt = 0; mt < 4; ++mt)
#pragma unroll
      for (int j = 0; j < 4; ++j) {
        float v = elu_f(acc[mt][nt][j] + bias);
        As[(mt * 16 + lk * 4 + j) * 264 + col] = f2bf(v);
      }
  }
  __syncthreads();

  // GEMM2: H[64,256] x W2b[256,128]; wave w owns cols [32w, 32w+32)
  f32x4 acc2[4][2];
#pragma unroll
  for (int mt = 0; mt < 4; ++mt)
#pragma unroll
    for (int nt = 0; nt < 2; ++nt) acc2[mt][nt] = zero4;
#pragma unroll
  for (int kt = 0; kt < 8; ++kt) {
    short8* bc = (kt & 1) ? bB : bA;
    short8* bn = (kt & 1) ? bA : bB;
    if (kt < 7) {
#pragma unroll
      for (int n = 0; n < 2; ++n) bn[n] = *(const short8*)(B2 + n * 4096 + (kt + 1) * 512);
    }
    short8 a[4];
#pragma unroll
    for (int mt = 0; mt < 4; ++mt)
      a[mt] = *(const short8*)(&As[(mt * 16 + lr) * 264 + kt * 32 + lk * 8]);
#pragma unroll
    for (int mt = 0; mt < 4; ++mt)
#pragma unroll
      for (int nt = 0; nt < 2; ++nt)
        acc2[mt][nt] = __builtin_amdgcn_mfma_f32_16x16x32_bf16(a[mt], bc[nt], acc2[mt][nt], 0, 0, 0);
  }

  // epilogue2: bias + store
#pragma unroll
  for (int nt = 0; nt < 2; ++nt) {
    int col = w * 32 + nt * 16 + lr;
    float bias = b2b[col];
#pragma unroll
    for (int mt = 0; mt < 4; ++mt)
#pragma unroll
      for (int j = 0; j < 4; ++j) {
        int node = n0 + mt * 16 + lk * 4 + j;
        if (node < N) out[(size_t)node * 128 + col] = acc2[mt][nt][j] + bias;
      }
  }
}

extern "C" void kernel_launch(void* const* d_in, const int* in_sizes, int n_in,
                              void* d_out, int out_size, void* d_ws, size_t ws_size,
                              hipStream_t stream) {
  const float* x = (const float*)d_in[0];
  const int* ei = (const int*)d_in[1];
  const float* eattr = (const float*)d_in[2];
  const float* W1a = (const float*)d_in[5];
  const float* b1a = (const float*)d_in[6];
  const float* W1b = (const float*)d_in[7];
  const float* b1b = (const float*)d_in[8];
  const float* W2a = (const float*)d_in[9];
  const float* b2a = (const float*)d_in[10];
  const float* W2b = (const float*)d_in[11];
  const float* b2b = (const float*)d_in[12];

  const int N = in_sizes[0] / 128;   // 25000
  const int E = in_sizes[2] / 128;   // 400000

  char* ws = (char*)d_ws;
  float* agg = (float*)ws;                              // N*256 f32 (sum of elu(h1))
  size_t off = (size_t)N * 256 * 4;
  int* cntbuf = (int*)(ws + off); off += (size_t)N * 4;
  int* startA = (int*)(ws + off); off += (size_t)(N + 1) * 4;
  int* offs   = (int*)(ws + off); off += (size_t)N * 4;
  int* eid    = (int*)(ws + off); off += (size_t)E * 4;
  off = (off + 255) & ~(size_t)255;
  unsigned short* w1aP = (unsigned short*)(ws + off); off += 256 * 256 * 2;
  unsigned short* w1bP = (unsigned short*)(ws + off); off += 256 * 256 * 2;
  unsigned short* w2aP = (unsigned short*)(ws + off); off += 384 * 256 * 2;
  unsigned short* w2bP = (unsigned short*)(ws + off);

  // zero only cnt via memset (100 KB); agg zeroing is parallelized inside prep.
  (void)hipMemsetAsync(cntbuf, 0, (size_t)N * 4, stream);

  const int hb = (E + 255) / 256;                 // hist blocks
  const int aggN = N * 256;                       // f32 elements in agg
  const int zb = (aggN / 4 + 255) / 256;          // agg-zero blocks (fvec4/thread)

  prep_kernel<<<1024 + hb + zb, 256, 0, stream>>>(
      W1a, W1b, W2a, W2b, w1aP, w1bP, w2aP, w2bP, ei + E, cntbuf, E, agg, aggN, hb);

  scan_kernel<<<1, 1024, 0, stream>>>(cntbuf, startA, offs, N, E);
  eid_kernel<<<hb, 256, 0, stream>>>(ei + E, offs, eid, E);

  edge_mlp_kernel<<<E / 64, 256, 0, stream>>>(x, ei, ei + E, eattr, b1a, w1aP, eid, agg);

  node_mlp_kernel<<<(N + 63) / 64, 256, 0, stream>>>(x, agg, startA, b1b, b2a, b2b,
                                                     w1bP, w2aP, w2bP, (float*)d_out, N);
}

// Round 13
// 260.791 us; speedup vs baseline: 1.8449x; 1.0348x over previous
//
#include <hip/hip_runtime.h>
#include <hip/hip_bf16.h>
#include <stdint.h>

typedef short short8 __attribute__((ext_vector_type(8)));
typedef float f32x4 __attribute__((ext_vector_type(4)));
typedef float fvec4 __attribute__((ext_vector_type(4)));
typedef unsigned short us4 __attribute__((ext_vector_type(4)));

// native float->bf16 (RNE)
static __device__ __forceinline__ unsigned short f2bf(float f) {
  return __bfloat16_as_ushort(__float2bfloat16(f));
}

static __device__ __forceinline__ float bf2f(unsigned short u) {
  union { uint32_t u; float f; } v; v.u = (uint32_t)u << 16;
  return v.f;
}

// fast ELU: __expf -> v_exp_f32. |err| ~1e-7, fine vs 2e-2 threshold.
static __device__ __forceinline__ float elu_f(float v) {
  return v > 0.0f ? v : __expf(v) - 1.0f;
}

// Fused prep, three block ranges running concurrently:
//   [0, 1024)            : pack all 4 weights into MFMA B-fragment order
//   [1024, 1024+hb)      : histogram dst counts
//   [1024+hb, ...)       : zero agg (N*256 f32) with fvec4 stores
__global__ void prep_kernel(const float* __restrict__ W1a, const float* __restrict__ W1b,
                            const float* __restrict__ W2a, const float* __restrict__ W2b,
                            unsigned short* __restrict__ w1aP, unsigned short* __restrict__ w1bP,
                            unsigned short* __restrict__ w2aP, unsigned short* __restrict__ w2bP,
                            const int* __restrict__ col_idx, int* __restrict__ cnt, int E,
                            float* __restrict__ agg, int aggN, int hb) {
  int b = blockIdx.x;
  if (b < 1024) {
    int p = b * 256 + threadIdx.x;
    const float* W; unsigned short* dst; int KT, Nc, q;
    if (p < 65536)       { W = W1a; dst = w1aP; KT = 8;  Nc = 256; q = p; }
    else if (p < 131072) { W = W1b; dst = w1bP; KT = 8;  Nc = 256; q = p - 65536; }
    else if (p < 229376) { W = W2a; dst = w2aP; KT = 12; Nc = 256; q = p - 131072; }
    else                 { W = W2b; dst = w2bP; KT = 8;  Nc = 128; q = p - 229376; }
    int i = q & 7;
    int l = (q >> 3) & 63;
    int rest = q >> 9;
    int kt = rest % KT;
    int nt = rest / KT;
    dst[q] = f2bf(W[(size_t)(kt * 32 + (l >> 4) * 8 + i) * Nc + nt * 16 + (l & 15)]);
  } else if (b < 1024 + hb) {
    int i = (b - 1024) * 256 + threadIdx.x;
    if (i < E) atomicAdd(&cnt[col_idx[i]], 1);
  } else {
    int idx = (b - 1024 - hb) * 256 + threadIdx.x;  // fvec4 index
    if (idx * 4 < aggN) {
      fvec4 z = {0.f, 0.f, 0.f, 0.f};
      *(fvec4*)(agg + (size_t)idx * 4) = z;
    }
  }
}

// single-launch scan: each thread serially owns a chunk, one 1024-wide block scan.
__global__ __launch_bounds__(1024) void scan_kernel(const int* __restrict__ cnt,
                                                    int* __restrict__ startA,
                                                    int* __restrict__ offs, int N, int E) {
  __shared__ int partial[1024];
  const int t = threadIdx.x;
  const int chunk = (N + 1023) >> 10;
  const int base = t * chunk;
  int s = 0;
  for (int i = 0; i < chunk; ++i) {
    int idx = base + i;
    if (idx < N) s += cnt[idx];
  }
  partial[t] = s;
  __syncthreads();
  for (int o = 1; o < 1024; o <<= 1) {
    int a = (t >= o) ? partial[t - o] : 0;
    __syncthreads();
    partial[t] += a;
    __syncthreads();
  }
  int run = partial[t] - s;
  for (int i = 0; i < chunk; ++i) {
    int idx = base + i;
    if (idx < N) {
      startA[idx] = run;
      offs[idx] = run;
      run += cnt[idx];
    }
  }
  if (t == 0) startA[N] = E;
}

// dst-sorted edge list: eid[csr_slot] = edge
__global__ void eid_kernel(const int* __restrict__ col_idx, int* __restrict__ offs,
                           int* __restrict__ eid, int E) {
  int i = blockIdx.x * blockDim.x + threadIdx.x;
  if (i < E) eid[atomicAdd(&offs[col_idx[i]], 1)] = i;
}

#define LDA 264  // 256 + 8 pad (bf16 elems); 528B row stride, 16B aligned
#define EBR 32   // CSR slots per block (small tile -> high block concurrency)

// 32 dst-sorted CSR slots/block, 4 waves; wave w owns output cols [64w,64w+64),
// rows 0..32 (acc[2][4]). GEMM1 + ELU + segmented reduce (W1b applied post-mean
// in node kernel). Interior segments: plain stores; boundary segments: atomicAdd.
// LDS ~17KB -> up to 6 blocks/CU at launch_bounds(256,6): ~1.7x the wave
// concurrency of the EB=64 version (latency-hiding is the binding resource).
__global__ __launch_bounds__(256, 6) void edge_mlp_kernel(
    const float* __restrict__ x, const int* __restrict__ row_idx,
    const int* __restrict__ col_idx, const float* __restrict__ eattr,
    const float* __restrict__ b1a,
    const unsigned short* __restrict__ w1aP,
    const int* __restrict__ eid, float* __restrict__ agg) {
  __shared__ __align__(16) unsigned short As[EBR * LDA];
  __shared__ int rowi[EBR];
  __shared__ int eidx[EBR];
  __shared__ int dsts[EBR];
  const int t = threadIdx.x;
  const int e0 = blockIdx.x * EBR;

  if (t < EBR) {
    int e = eid[e0 + t];
    eidx[t] = e;
    rowi[t] = row_idx[e];
    dsts[t] = col_idx[e];  // non-decreasing across the tile (CSR order)
  }

  const int w = t >> 6, l = t & 63;
  const int lr = l & 15, lk = l >> 4;
  const unsigned short* B1 = w1aP + (size_t)(w * 32) * 512 + (size_t)l * 8;

  short8 bA[4], bB[4];
#pragma unroll
  for (int n = 0; n < 4; ++n) bA[n] = *(const short8*)(B1 + n * 4096);

  __syncthreads();

  // stage A: [32 slots][256 feats] as bf16 (x[row[eid]] | edge_attr[eid])
  for (int idx = t; idx < EBR * 64; idx += 256) {
    int e = idx >> 6, c4 = idx & 63;
    fvec4 v;
    if (c4 < 32)
      v = *(const fvec4*)(x + (size_t)rowi[e] * 128 + c4 * 4);
    else
      v = __builtin_nontemporal_load((const fvec4*)(eattr + (size_t)eidx[e] * 128 + (c4 - 32) * 4));
    us4 o;
    o.x = f2bf(v.x); o.y = f2bf(v.y); o.z = f2bf(v.z); o.w = f2bf(v.w);
    *(us4*)(&As[e * LDA + c4 * 4]) = o;
  }
  __syncthreads();

  f32x4 acc[2][4];
  const f32x4 zero4 = {0.f, 0.f, 0.f, 0.f};
#pragma unroll
  for (int mt = 0; mt < 2; ++mt)
#pragma unroll
    for (int nt = 0; nt < 4; ++nt) acc[mt][nt] = zero4;

  // GEMM1: [32,256] x W1a[256,256], B double-buffered
#pragma unroll
  for (int kt = 0; kt < 8; ++kt) {
    short8* bc = (kt & 1) ? bB : bA;
    short8* bn = (kt & 1) ? bA : bB;
    if (kt < 7) {
#pragma unroll
      for (int n = 0; n < 4; ++n) bn[n] = *(const short8*)(B1 + n * 4096 + (kt + 1) * 512);
    }
    short8 a[2];
#pragma unroll
    for (int mt = 0; mt < 2; ++mt)
      a[mt] = *(const short8*)(&As[(mt * 16 + lr) * LDA + kt * 32 + lk * 8]);
#pragma unroll
    for (int mt = 0; mt < 2; ++mt)
#pragma unroll
      for (int nt = 0; nt < 4; ++nt)
        acc[mt][nt] = __builtin_amdgcn_mfma_f32_16x16x32_bf16(a[mt], bc[nt], acc[mt][nt], 0, 0, 0);
  }
  __syncthreads();  // all waves done reading As

  // epilogue: bias + ELU -> bf16 back into As
#pragma unroll
  for (int nt = 0; nt < 4; ++nt) {
    int col = w * 64 + nt * 16 + lr;
    float bias = b1a[col];
#pragma unroll
    for (int mt = 0; mt < 2; ++mt)
#pragma unroll
      for (int j = 0; j < 4; ++j) {
        float v = elu_f(acc[mt][nt][j] + bias);
        As[(mt * 16 + lk * 4 + j) * LDA + col] = f2bf(v);
      }
  }
  __syncthreads();

  // segmented reduction over dst-runs; thread t owns column t.
  {
    const int col = t;
    float run = 0.f;
    int prev = dsts[0];
    int segstart = 0;
#pragma unroll 8
    for (int r = 0; r < EBR; ++r) {
      int d = dsts[r];
      if (d != prev) {
        if (segstart == 0)
          atomicAdd(&agg[(size_t)prev * 256 + col], run);
        else
          agg[(size_t)prev * 256 + col] = run;  // interior: sole owner
        run = 0.f;
        prev = d;
        segstart = r;
      }
      run += bf2f(As[r * LDA + col]);
    }
    atomicAdd(&agg[(size_t)prev * 256 + col], run);  // tail touches tile edge
  }
}

#define LDN 392  // 384 + 8 pad

// 64 nodes/block, 4 waves.
// Phase A: magg = agg/cnt -> GEMM x W1b -> u (+b1b, gated).
// Phase B: [x | u] -> MLP2 (GEMM 384->256, ELU, GEMM 256->128).
// [proven: unchanged since R10]
__global__ __launch_bounds__(256, 3) void node_mlp_kernel(
    const float* __restrict__ x, const float* __restrict__ agg,
    const int* __restrict__ startA, const float* __restrict__ b1b,
    const float* __restrict__ b2a, const float* __restrict__ b2b,
    const unsigned short* __restrict__ w1bP, const unsigned short* __restrict__ w2aP,
    const unsigned short* __restrict__ w2bP,
    float* __restrict__ out, int N) {
  __shared__ __align__(16) unsigned short As[64 * LDN];
  __shared__ float inv64[64];
  const int t = threadIdx.x;
  const int n0 = blockIdx.x * 64;

  const int w = t >> 6, l = t & 63;
  const int lr = l & 15, lk = l >> 4;
  const unsigned short* B0 = w1bP + (size_t)(w * 32) * 512 + (size_t)l * 8;
  const unsigned short* B1 = w2aP + (size_t)(w * 48) * 512 + (size_t)l * 8;
  const unsigned short* B2 = w2bP + (size_t)(w * 16) * 512 + (size_t)l * 8;

  if (t < 64) {
    int node = n0 + t;
    int cn = (node < N) ? (startA[node + 1] - startA[node]) : 0;
    inv64[t] = cn > 0 ? 1.0f / (float)cn : 0.f;
  }

  short8 bA[4], bB[4];
#pragma unroll
  for (int n = 0; n < 4; ++n) bA[n] = *(const short8*)(B0 + n * 4096);

  __syncthreads();  // inv64 ready

  // stage magg: [64][264] bf16 = agg[node]*inv
  for (int idx = t; idx < 64 * 64; idx += 256) {
    int nn = idx >> 6, c4 = idx & 63;
    int node = n0 + nn;
    fvec4 v = {0.f, 0.f, 0.f, 0.f};
    if (node < N) {
      float inv = inv64[nn];
      fvec4 a = *(const fvec4*)(agg + (size_t)node * 256 + c4 * 4);
      v.x = a.x * inv; v.y = a.y * inv; v.z = a.z * inv; v.w = a.w * inv;
    }
    us4 o;
    o.x = f2bf(v.x); o.y = f2bf(v.y); o.z = f2bf(v.z); o.w = f2bf(v.w);
    *(us4*)(&As[nn * 264 + c4 * 4]) = o;
  }
  __syncthreads();

  const f32x4 zero4 = {0.f, 0.f, 0.f, 0.f};
  f32x4 accU[4][4];
#pragma unroll
  for (int mt = 0; mt < 4; ++mt)
#pragma unroll
    for (int nt = 0; nt < 4; ++nt) accU[mt][nt] = zero4;

  // GEMM-u: magg[64,256] x W1b[256,256]
#pragma unroll
  for (int kt = 0; kt < 8; ++kt) {
    short8* bc = (kt & 1) ? bB : bA;
    short8* bn = (kt & 1) ? bA : bB;
    if (kt < 7) {
#pragma unroll
      for (int n = 0; n < 4; ++n) bn[n] = *(const short8*)(B0 + n * 4096 + (kt + 1) * 512);
    }
    short8 a[4];
#pragma unroll
    for (int mt = 0; mt < 4; ++mt)
      a[mt] = *(const short8*)(&As[(mt * 16 + lr) * 264 + kt * 32 + lk * 8]);
#pragma unroll
    for (int mt = 0; mt < 4; ++mt)
#pragma unroll
      for (int nt = 0; nt < 4; ++nt)
        accU[mt][nt] = __builtin_amdgcn_mfma_f32_16x16x32_bf16(a[mt], bc[nt], accU[mt][nt], 0, 0, 0);
  }

  // prefetch W2a kt=0
#pragma unroll
  for (int n = 0; n < 4; ++n) bA[n] = *(const short8*)(B1 + n * 6144);

  __syncthreads();  // magg reads done; As re-purposed at stride 392

  // stage x into cols [0,128) of the [64][392] buffer
  for (int idx = t; idx < 64 * 32; idx += 256) {
    int nn = idx >> 5, c4 = idx & 31;
    int node = n0 + nn;
    fvec4 v = {0.f, 0.f, 0.f, 0.f};
    if (node < N) v = *(const fvec4*)(x + (size_t)node * 128 + c4 * 4);
    us4 o;
    o.x = f2bf(v.x); o.y = f2bf(v.y); o.z = f2bf(v.z); o.w = f2bf(v.w);
    *(us4*)(&As[nn * LDN + c4 * 4]) = o;
  }

  // write u = accU + b1b (gated by cnt>0) into cols [128,384)
#pragma unroll
  for (int nt = 0; nt < 4; ++nt) {
    int col = w * 64 + nt * 16 + lr;
    float bias = b1b[col];
#pragma unroll
    for (int mt = 0; mt < 4; ++mt)
#pragma unroll
      for (int j = 0; j < 4; ++j) {
        int row = mt * 16 + lk * 4 + j;
        float g = inv64[row] > 0.f ? 1.f : 0.f;
        As[row * LDN + 128 + col] = f2bf(accU[mt][nt][j] + g * bias);
      }
  }
  __syncthreads();

  f32x4 acc[4][4];
#pragma unroll
  for (int mt = 0; mt < 4; ++mt)
#pragma unroll
    for (int nt = 0; nt < 4; ++nt) acc[mt][nt] = zero4;

  // MLP2 GEMM1: [64,384] x W2a[384,256]
#pragma unroll
  for (int kt = 0; kt < 12; ++kt) {
    short8* bc = (kt & 1) ? bB : bA;
    short8* bn = (kt & 1) ? bA : bB;
    if (kt < 11) {
#pragma unroll
      for (int n = 0; n < 4; ++n) bn[n] = *(const short8*)(B1 + n * 6144 + (kt + 1) * 512);
    }
    short8 a[4];
#pragma unroll
    for (int mt = 0; mt < 4; ++mt)
      a[mt] = *(const short8*)(&As[(mt * 16 + lr) * LDN + kt * 32 + lk * 8]);
#pragma unroll
    for (int mt = 0; mt < 4; ++mt)
#pragma unroll
      for (int nt = 0; nt < 4; ++nt)
        acc[mt][nt] = __builtin_amdgcn_mfma_f32_16x16x32_bf16(a[mt], bc[nt], acc[mt][nt], 0, 0, 0);
  }

#pragma unroll
  for (int n = 0; n < 2; ++n) bA[n] = *(const short8*)(B2 + n * 4096);

  __syncthreads();

  // epilogue1: bias + ELU -> H (reuse As, stride 264)
#pragma unroll
  for (int nt = 0; nt < 4; ++nt) {
    int col = w * 64 + nt * 16 + lr;
    float bias = b2a[col];
#pragma unroll
    for (int mt = 0; mt < 4; ++mt)
#pragma unroll
      for (int j = 0; j < 4; ++j) {
        float v = elu_f(acc[mt][nt][j] + bias);
        As[(mt * 16 + lk * 4 + j) * 264 + col] = f2bf(v);
      }
  }
  __syncthreads();

  // GEMM2: H[64,256] x W2b[256,128]; wave w owns cols [32w, 32w+32)
  f32x4 acc2[4][2];
#pragma unroll
  for (int mt = 0; mt < 4; ++mt)
#pragma unroll
    for (int nt = 0; nt < 2; ++nt) acc2[mt][nt] = zero4;
#pragma unroll
  for (int kt = 0; kt < 8; ++kt) {
    short8* bc = (kt & 1) ? bB : bA;
    short8* bn = (kt & 1) ? bA : bB;
    if (kt < 7) {
#pragma unroll
      for (int n = 0; n < 2; ++n) bn[n] = *(const short8*)(B2 + n * 4096 + (kt + 1) * 512);
    }
    short8 a[4];
#pragma unroll
    for (int mt = 0; mt < 4; ++mt)
      a[mt] = *(const short8*)(&As[(mt * 16 + lr) * 264 + kt * 32 + lk * 8]);
#pragma unroll
    for (int mt = 0; mt < 4; ++mt)
#pragma unroll
      for (int nt = 0; nt < 2; ++nt)
        acc2[mt][nt] = __builtin_amdgcn_mfma_f32_16x16x32_bf16(a[mt], bc[nt], acc2[mt][nt], 0, 0, 0);
  }

  // epilogue2: bias + store
#pragma unroll
  for (int nt = 0; nt < 2; ++nt) {
    int col = w * 32 + nt * 16 + lr;
    float bias = b2b[col];
#pragma unroll
    for (int mt = 0; mt < 4; ++mt)
#pragma unroll
      for (int j = 0; j < 4; ++j) {
        int node = n0 + mt * 16 + lk * 4 + j;
        if (node < N) out[(size_t)node * 128 + col] = acc2[mt][nt][j] + bias;
      }
  }
}

extern "C" void kernel_launch(void* const* d_in, const int* in_sizes, int n_in,
                              void* d_out, int out_size, void* d_ws, size_t ws_size,
                              hipStream_t stream) {
  const float* x = (const float*)d_in[0];
  const int* ei = (const int*)d_in[1];
  const float* eattr = (const float*)d_in[2];
  const float* W1a = (const float*)d_in[5];
  const float* b1a = (const float*)d_in[6];
  const float* W1b = (const float*)d_in[7];
  const float* b1b = (const float*)d_in[8];
  const float* W2a = (const float*)d_in[9];
  const float* b2a = (const float*)d_in[10];
  const float* W2b = (const float*)d_in[11];
  const float* b2b = (const float*)d_in[12];

  const int N = in_sizes[0] / 128;   // 25000
  const int E = in_sizes[2] / 128;   // 400000

  char* ws = (char*)d_ws;
  float* agg = (float*)ws;                              // N*256 f32 (sum of elu(h1))
  size_t off = (size_t)N * 256 * 4;
  int* cntbuf = (int*)(ws + off); off += (size_t)N * 4;
  int* startA = (int*)(ws + off); off += (size_t)(N + 1) * 4;
  int* offs   = (int*)(ws + off); off += (size_t)N * 4;
  int* eid    = (int*)(ws + off); off += (size_t)E * 4;
  off = (off + 255) & ~(size_t)255;
  unsigned short* w1aP = (unsigned short*)(ws + off); off += 256 * 256 * 2;
  unsigned short* w1bP = (unsigned short*)(ws + off); off += 256 * 256 * 2;
  unsigned short* w2aP = (unsigned short*)(ws + off); off += 384 * 256 * 2;
  unsigned short* w2bP = (unsigned short*)(ws + off);

  // zero only cnt via memset (100 KB); agg zeroing is parallelized inside prep.
  (void)hipMemsetAsync(cntbuf, 0, (size_t)N * 4, stream);

  const int hb = (E + 255) / 256;                 // hist blocks
  const int aggN = N * 256;                       // f32 elements in agg
  const int zb = (aggN / 4 + 255) / 256;          // agg-zero blocks (fvec4/thread)

  prep_kernel<<<1024 + hb + zb, 256, 0, stream>>>(
      W1a, W1b, W2a, W2b, w1aP, w1bP, w2aP, w2bP, ei + E, cntbuf, E, agg, aggN, hb);

  scan_kernel<<<1, 1024, 0, stream>>>(cntbuf, startA, offs, N, E);
  eid_kernel<<<hb, 256, 0, stream>>>(ei + E, offs, eid, E);

  edge_mlp_kernel<<<E / EBR, 256, 0, stream>>>(x, ei, ei + E, eattr, b1a, w1aP, eid, agg);

  node_mlp_kernel<<<(N + 63) / 64, 256, 0, stream>>>(x, agg, startA, b1b, b2a, b2b,
                                                     w1bP, w2aP, w2bP, (float*)d_out, N);
}